// Round 1
// baseline (2028.165 us; speedup 1.0000x reference)
//
#include <hip/hip_runtime.h>

#define BN_EPS 1e-5f
#define B_ 2
#define C_ 512
#define CK_ 64
#define N_ 4096

// ---------------------------------------------------------------------------
// K0: fold BN scale into conv weights, transpose to [j][c][tap][co]; shift[j][co]
// ---------------------------------------------------------------------------
__global__ __launch_bounds__(256) void prep_weights_kernel(
    const float* __restrict__ w1, const float* __restrict__ g1, const float* __restrict__ b1,
    const float* __restrict__ m1, const float* __restrict__ v1,
    const float* __restrict__ w2, const float* __restrict__ g2, const float* __restrict__ b2,
    const float* __restrict__ m2, const float* __restrict__ v2,
    float* __restrict__ wT, float* __restrict__ shiftA)
{
    int idx = blockIdx.x * 256 + threadIdx.x;
    const int total = 2 * C_ * 9 * CK_;
    if (idx < total) {
        int co = idx & 63;
        int t9 = (idx >> 6) % 9;
        int c  = (idx / (9 * 64)) % C_;
        int j  = idx / (9 * 64 * C_);
        const float* w = j ? w2 : w1;
        const float* g = j ? g2 : g1;
        const float* v = j ? v2 : v1;
        float scale = g[co] / sqrtf(v[co] + BN_EPS);
        wT[idx] = w[((size_t)co * C_ + c) * 9 + t9] * scale;
    }
    if (idx < 2 * CK_) {
        int j = idx >> 6, co = idx & 63;
        const float* g = j ? g2 : g1;
        const float* v = j ? v2 : v1;
        const float* bb = j ? b2 : b1;
        const float* mm = j ? m2 : m1;
        float scale = g[co] / sqrtf(v[co] + BN_EPS);
        shiftA[idx] = bb[co] - mm[co] * scale;
    }
}

// ---------------------------------------------------------------------------
// K1: conv3x3 + BN(shift) + SiLU.  Block = (b, j, h-row): 64 co x 64 w outputs.
// Thread owns 4co x 4w. Channels staged 8 at a time (x rows + weights in LDS).
// ---------------------------------------------------------------------------
__global__ __launch_bounds__(256) void conv_bn_silu_kernel(
    const float* __restrict__ x, const float* __restrict__ wT,
    const float* __restrict__ shiftA, float* __restrict__ y1, float* __restrict__ y2)
{
    __shared__ float xs[8][3][66];
    __shared__ __align__(16) float ws[8 * 9 * 64];
    int blk = blockIdx.x;
    int h = blk & 63;
    int j = (blk >> 6) & 1;
    int b = blk >> 7;
    int t = threadIdx.x;
    int w0  = (t & 15) * 4;
    int co0 = (t >> 4) * 4;
    float acc[4][4] = {};
    const float* xb = x + (size_t)b * C_ * N_;
    const float* wj = wT + (size_t)j * C_ * 9 * 64;

    for (int cc = 0; cc < C_ / 8; ++cc) {
        for (int i = t; i < 8 * 3 * 64; i += 256) {
            int c = i / 192;
            int r = (i / 64) % 3;
            int ww = i & 63;
            int row = h - 1 + r;
            float val = 0.f;
            if (row >= 0 && row < 64)
                val = xb[((size_t)(cc * 8 + c) * 64 + row) * 64 + ww];
            xs[c][r][ww + 1] = val;
        }
        if (t < 24) {
            int c = t / 3, r = t - c * 3;
            xs[c][r][0]  = 0.f;
            xs[c][r][65] = 0.f;
        }
        {
            const float4* src = (const float4*)(wj + cc * 4608);
            float4* dst = (float4*)ws;
            for (int i = t; i < 1152; i += 256) dst[i] = src[i];
        }
        __syncthreads();
        #pragma unroll
        for (int c = 0; c < 8; ++c) {
            float xv[3][6];
            #pragma unroll
            for (int r = 0; r < 3; ++r)
                #pragma unroll
                for (int q = 0; q < 6; ++q)
                    xv[r][q] = xs[c][r][w0 + q];
            #pragma unroll
            for (int tap = 0; tap < 9; ++tap) {
                int dh = tap / 3, dw = tap - dh * 3;
                float4 wv = *(const float4*)&ws[(c * 9 + tap) * 64 + co0];
                #pragma unroll
                for (int q = 0; q < 4; ++q) {
                    float xq = xv[dh][q + dw];
                    acc[0][q] += wv.x * xq;
                    acc[1][q] += wv.y * xq;
                    acc[2][q] += wv.z * xq;
                    acc[3][q] += wv.w * xq;
                }
            }
        }
        __syncthreads();
    }
    float* yj = j ? y2 : y1;
    #pragma unroll
    for (int o = 0; o < 4; ++o) {
        float sh = shiftA[j * 64 + co0 + o];
        #pragma unroll
        for (int q = 0; q < 4; ++q) {
            float yv = acc[o][q] + sh;
            float sg = 1.f / (1.f + __expf(-yv));
            yj[((size_t)b * 64 + co0 + o) * N_ + h * 64 + w0 + q] = yv * sg;
        }
    }
}

// ---------------------------------------------------------------------------
// K2: softmax row stats.  Block = (b, 64-row n-tile).  Online max/sum over all m.
// c[n,m] = sum_k y2[k,n] * y1[k,m]   (K=64, full K in one pass)
// ---------------------------------------------------------------------------
__global__ __launch_bounds__(256) void softmax_stats_kernel(
    const float* __restrict__ y1, const float* __restrict__ y2,
    float* __restrict__ rowmax, float* __restrict__ rowinv)
{
    __shared__ __align__(16) float y2s[64][64];
    __shared__ __align__(16) float y1s[64][64];
    __shared__ float red[64][16][2];
    int b  = blockIdx.x >> 6;
    int nt = blockIdx.x & 63;
    int n0 = nt * 64;
    int t = threadIdx.x;
    int tn4 = (t >> 4) * 4;
    int tm4 = (t & 15) * 4;

    for (int i = t; i < 4096; i += 256) {
        int k = i >> 6, nn = i & 63;
        y2s[k][nn] = y2[((size_t)b * 64 + k) * N_ + n0 + nn];
    }
    float runmax[4], runsum[4];
    #pragma unroll
    for (int i = 0; i < 4; ++i) { runmax[i] = -3.0e38f; runsum[i] = 0.f; }

    for (int mt = 0; mt < 64; ++mt) {
        __syncthreads();
        for (int i = t; i < 4096; i += 256) {
            int k = i >> 6, mm = i & 63;
            y1s[k][mm] = y1[((size_t)b * 64 + k) * N_ + mt * 64 + mm];
        }
        __syncthreads();
        float cr[4][4] = {};
        #pragma unroll 16
        for (int k = 0; k < 64; ++k) {
            float4 a  = *(const float4*)&y2s[k][tn4];
            float4 bv = *(const float4*)&y1s[k][tm4];
            cr[0][0] += a.x*bv.x; cr[0][1] += a.x*bv.y; cr[0][2] += a.x*bv.z; cr[0][3] += a.x*bv.w;
            cr[1][0] += a.y*bv.x; cr[1][1] += a.y*bv.y; cr[1][2] += a.y*bv.z; cr[1][3] += a.y*bv.w;
            cr[2][0] += a.z*bv.x; cr[2][1] += a.z*bv.y; cr[2][2] += a.z*bv.z; cr[2][3] += a.z*bv.w;
            cr[3][0] += a.w*bv.x; cr[3][1] += a.w*bv.y; cr[3][2] += a.w*bv.z; cr[3][3] += a.w*bv.w;
        }
        #pragma unroll
        for (int i = 0; i < 4; ++i) {
            float mx = fmaxf(fmaxf(cr[i][0], cr[i][1]), fmaxf(cr[i][2], cr[i][3]));
            float M  = fmaxf(runmax[i], mx);
            float sc = __expf(runmax[i] - M);
            float s  = __expf(cr[i][0] - M) + __expf(cr[i][1] - M)
                     + __expf(cr[i][2] - M) + __expf(cr[i][3] - M);
            runsum[i] = runsum[i] * sc + s;
            runmax[i] = M;
        }
    }
    int tm = t & 15;
    #pragma unroll
    for (int i = 0; i < 4; ++i) {
        red[tn4 + i][tm][0] = runmax[i];
        red[tn4 + i][tm][1] = runsum[i];
    }
    __syncthreads();
    if (t < 64) {
        float M = -3.0e38f;
        #pragma unroll
        for (int q = 0; q < 16; ++q) M = fmaxf(M, red[t][q][0]);
        float S = 0.f;
        #pragma unroll
        for (int q = 0; q < 16; ++q) S += red[t][q][1] * __expf(red[t][q][0] - M);
        rowmax[b * N_ + n0 + t] = M;
        rowinv[b * N_ + n0 + t] = 1.f / S;
    }
}

// ---------------------------------------------------------------------------
// K3: out[b,c,m] = sum_n x[b,c,n] * exp(c[n,m]-rowmax[n])*rowinv[n]
// Block = (b, 128-c tile, 128-m tile).  Loop n in 32-tiles: recompute c tile,
// exponentiate into LDS, then register-blocked 8c x 4m GEMM.
// ---------------------------------------------------------------------------
__global__ __launch_bounds__(512) void attn_out_kernel(
    const float* __restrict__ x, const float* __restrict__ y1, const float* __restrict__ y2,
    const float* __restrict__ rowmax, const float* __restrict__ rowinv,
    float* __restrict__ out)
{
    __shared__ __align__(16) float y1s[64][128];
    __shared__ __align__(16) float y2s[64][32];
    __shared__ __align__(16) float cwS[32][128];
    __shared__ __align__(16) float xsm[32][132];
    int blk = blockIdx.x;
    int mb = blk & 31;
    int cb = (blk >> 5) & 3;
    int b  = blk >> 7;
    int m0 = mb * 128;
    int c0 = cb * 128;
    int t = threadIdx.x;
    int tcg8 = (t >> 5) * 8;
    int tmg4 = (t & 31) * 4;
    int cn  = t >> 4;          // 0..31: c-compute row
    int cmq = (t & 15) * 8;    // c-compute m base

    for (int i = t; i < 64 * 128; i += 512) {
        int k = i >> 7, mm = i & 127;
        y1s[k][mm] = y1[((size_t)b * 64 + k) * N_ + m0 + mm];
    }
    float acc[8][4] = {};
    const float* xb = x + ((size_t)b * C_ + c0) * N_;

    for (int nt = 0; nt < 128; ++nt) {
        int n0 = nt * 32;
        __syncthreads();
        for (int i = t; i < 64 * 32; i += 512) {
            int k = i >> 5, nn = i & 31;
            y2s[k][nn] = y2[((size_t)b * 64 + k) * N_ + n0 + nn];
        }
        for (int i = t; i < 128 * 32; i += 512) {
            int c = i >> 5, nn = i & 31;
            xsm[nn][c] = xb[(size_t)c * N_ + n0 + nn];
        }
        __syncthreads();
        {
            float ca[8] = {};
            #pragma unroll 8
            for (int k = 0; k < 64; ++k) {
                float a   = y2s[k][cn];
                float4 b0 = *(const float4*)&y1s[k][cmq];
                float4 b1 = *(const float4*)&y1s[k][cmq + 4];
                ca[0] += a * b0.x; ca[1] += a * b0.y; ca[2] += a * b0.z; ca[3] += a * b0.w;
                ca[4] += a * b1.x; ca[5] += a * b1.y; ca[6] += a * b1.z; ca[7] += a * b1.w;
            }
            float Mn = rowmax[b * N_ + n0 + cn];
            float iv = rowinv[b * N_ + n0 + cn];
            float4 e0 = make_float4(__expf(ca[0]-Mn)*iv, __expf(ca[1]-Mn)*iv,
                                    __expf(ca[2]-Mn)*iv, __expf(ca[3]-Mn)*iv);
            float4 e1 = make_float4(__expf(ca[4]-Mn)*iv, __expf(ca[5]-Mn)*iv,
                                    __expf(ca[6]-Mn)*iv, __expf(ca[7]-Mn)*iv);
            *(float4*)&cwS[cn][cmq]     = e0;
            *(float4*)&cwS[cn][cmq + 4] = e1;
        }
        __syncthreads();
        #pragma unroll 4
        for (int nn = 0; nn < 32; ++nn) {
            float4 xa = *(const float4*)&xsm[nn][tcg8];
            float4 xc = *(const float4*)&xsm[nn][tcg8 + 4];
            float4 wv = *(const float4*)&cwS[nn][tmg4];
            acc[0][0] += xa.x*wv.x; acc[0][1] += xa.x*wv.y; acc[0][2] += xa.x*wv.z; acc[0][3] += xa.x*wv.w;
            acc[1][0] += xa.y*wv.x; acc[1][1] += xa.y*wv.y; acc[1][2] += xa.y*wv.z; acc[1][3] += xa.y*wv.w;
            acc[2][0] += xa.z*wv.x; acc[2][1] += xa.z*wv.y; acc[2][2] += xa.z*wv.z; acc[2][3] += xa.z*wv.w;
            acc[3][0] += xa.w*wv.x; acc[3][1] += xa.w*wv.y; acc[3][2] += xa.w*wv.z; acc[3][3] += xa.w*wv.w;
            acc[4][0] += xc.x*wv.x; acc[4][1] += xc.x*wv.y; acc[4][2] += xc.x*wv.z; acc[4][3] += xc.x*wv.w;
            acc[5][0] += xc.y*wv.x; acc[5][1] += xc.y*wv.y; acc[5][2] += xc.y*wv.z; acc[5][3] += xc.y*wv.w;
            acc[6][0] += xc.z*wv.x; acc[6][1] += xc.z*wv.y; acc[6][2] += xc.z*wv.z; acc[6][3] += xc.z*wv.w;
            acc[7][0] += xc.w*wv.x; acc[7][1] += xc.w*wv.y; acc[7][2] += xc.w*wv.z; acc[7][3] += xc.w*wv.w;
        }
    }
    #pragma unroll
    for (int q = 0; q < 8; ++q) {
        size_t row = (size_t)b * C_ + c0 + tcg8 + q;
        float4 o4 = make_float4(acc[q][0], acc[q][1], acc[q][2], acc[q][3]);
        *(float4*)&out[row * N_ + m0 + tmg4] = o4;
    }
}

// ---------------------------------------------------------------------------
extern "C" void kernel_launch(void* const* d_in, const int* in_sizes, int n_in,
                              void* d_out, int out_size, void* d_ws, size_t ws_size,
                              hipStream_t stream) {
    const float* x  = (const float*)d_in[0];
    const float* w1 = (const float*)d_in[1];
    const float* g1 = (const float*)d_in[2];
    const float* b1 = (const float*)d_in[3];
    const float* m1 = (const float*)d_in[4];
    const float* v1 = (const float*)d_in[5];
    const float* w2 = (const float*)d_in[6];
    const float* g2 = (const float*)d_in[7];
    const float* b2 = (const float*)d_in[8];
    const float* m2 = (const float*)d_in[9];
    const float* v2 = (const float*)d_in[10];
    float* out = (float*)d_out;

    float* ws = (float*)d_ws;
    float* wT     = ws;                       // 2*512*9*64 = 589824
    float* shiftA = wT + 589824;              // 128
    float* y1     = shiftA + 128;             // 2*64*4096 = 524288
    float* y2     = y1 + 524288;              // 524288
    float* rowmax = y2 + 524288;              // 8192
    float* rowinv = rowmax + 8192;            // 8192  (total ~6.6 MB)

    prep_weights_kernel<<<2304, 256, 0, stream>>>(w1, g1, b1, m1, v1,
                                                  w2, g2, b2, m2, v2, wT, shiftA);
    conv_bn_silu_kernel<<<256, 256, 0, stream>>>(x, wT, shiftA, y1, y2);
    softmax_stats_kernel<<<128, 256, 0, stream>>>(y1, y2, rowmax, rowinv);
    attn_out_kernel<<<256, 512, 0, stream>>>(x, y1, y2, rowmax, rowinv, out);
}

// Round 4
// 1119.004 us; speedup vs baseline: 1.8125x; 1.8125x over previous
//
#include <hip/hip_runtime.h>

#define BN_EPS 1e-5f
#define B_ 2
#define C_ 512
#define CK_ 64
#define N_ 4096

typedef unsigned short u16;
typedef unsigned int u32;
typedef _Float16 half8 __attribute__((ext_vector_type(8)));
typedef float f32x4 __attribute__((ext_vector_type(4)));

// ---------------------------------------------------------------------------
// K0: fold BN scale into conv weights, transpose to [j][c][tap][co]; shift[j][co]
// ---------------------------------------------------------------------------
__global__ __launch_bounds__(256) void prep_weights_kernel(
    const float* __restrict__ w1, const float* __restrict__ g1, const float* __restrict__ b1,
    const float* __restrict__ m1, const float* __restrict__ v1,
    const float* __restrict__ w2, const float* __restrict__ g2, const float* __restrict__ b2,
    const float* __restrict__ m2, const float* __restrict__ v2,
    float* __restrict__ wT, float* __restrict__ shiftA)
{
    int idx = blockIdx.x * 256 + threadIdx.x;
    const int total = 2 * C_ * 9 * CK_;
    if (idx < total) {
        int co = idx & 63;
        int t9 = (idx >> 6) % 9;
        int c  = (idx / (9 * 64)) % C_;
        int j  = idx / (9 * 64 * C_);
        const float* w = j ? w2 : w1;
        const float* g = j ? g2 : g1;
        const float* v = j ? v2 : v1;
        float scale = g[co] / sqrtf(v[co] + BN_EPS);
        wT[idx] = w[((size_t)co * C_ + c) * 9 + t9] * scale;
    }
    if (idx < 2 * CK_) {
        int j = idx >> 6, co = idx & 63;
        const float* g = j ? g2 : g1;
        const float* v = j ? v2 : v1;
        const float* bb = j ? b2 : b1;
        const float* mm = j ? m2 : m1;
        float scale = g[co] / sqrtf(v[co] + BN_EPS);
        shiftA[idx] = bb[co] - mm[co] * scale;
    }
}

// ---------------------------------------------------------------------------
// K0b: cast x (fp32) -> fp16, same [b][c][n] layout
// ---------------------------------------------------------------------------
__global__ __launch_bounds__(256) void cast_x_kernel(
    const float* __restrict__ x, u16* __restrict__ xh)
{
    int i = (blockIdx.x * 256 + threadIdx.x) * 8;   // 2*512*4096 = 4194304 elems
    float4 v0 = *(const float4*)(x + i);
    float4 v1 = *(const float4*)(x + i + 4);
    half8 h;
    h[0] = (_Float16)v0.x; h[1] = (_Float16)v0.y; h[2] = (_Float16)v0.z; h[3] = (_Float16)v0.w;
    h[4] = (_Float16)v1.x; h[5] = (_Float16)v1.y; h[6] = (_Float16)v1.z; h[7] = (_Float16)v1.w;
    *(half8*)(void*)(xh + i) = h;
}

// ---------------------------------------------------------------------------
// K1: conv3x3 + BN(shift) + SiLU.
// ---------------------------------------------------------------------------
__global__ __launch_bounds__(256) void conv_bn_silu_kernel(
    const float* __restrict__ x, const float* __restrict__ wT,
    const float* __restrict__ shiftA, float* __restrict__ y1, float* __restrict__ y2)
{
    __shared__ float xs[8][3][66];
    __shared__ __align__(16) float ws[8 * 9 * 64];
    int blk = blockIdx.x;
    int h = blk & 63;
    int j = (blk >> 6) & 1;
    int b = blk >> 7;
    int t = threadIdx.x;
    int w0  = (t & 15) * 4;
    int co0 = (t >> 4) * 4;
    float acc[4][4] = {};
    const float* xb = x + (size_t)b * C_ * N_;
    const float* wj = wT + (size_t)j * C_ * 9 * 64;

    for (int cc = 0; cc < C_ / 8; ++cc) {
        for (int i = t; i < 8 * 3 * 64; i += 256) {
            int c = i / 192;
            int r = (i / 64) % 3;
            int ww = i & 63;
            int row = h - 1 + r;
            float val = 0.f;
            if (row >= 0 && row < 64)
                val = xb[((size_t)(cc * 8 + c) * 64 + row) * 64 + ww];
            xs[c][r][ww + 1] = val;
        }
        if (t < 24) {
            int c = t / 3, r = t - c * 3;
            xs[c][r][0]  = 0.f;
            xs[c][r][65] = 0.f;
        }
        {
            const float4* src = (const float4*)(wj + cc * 4608);
            float4* dst = (float4*)ws;
            for (int i = t; i < 1152; i += 256) dst[i] = src[i];
        }
        __syncthreads();
        #pragma unroll
        for (int c = 0; c < 8; ++c) {
            float xv[3][6];
            #pragma unroll
            for (int r = 0; r < 3; ++r)
                #pragma unroll
                for (int q = 0; q < 6; ++q)
                    xv[r][q] = xs[c][r][w0 + q];
            #pragma unroll
            for (int tap = 0; tap < 9; ++tap) {
                int dh = tap / 3, dw = tap - dh * 3;
                float4 wv = *(const float4*)&ws[(c * 9 + tap) * 64 + co0];
                #pragma unroll
                for (int q = 0; q < 4; ++q) {
                    float xq = xv[dh][q + dw];
                    acc[0][q] += wv.x * xq;
                    acc[1][q] += wv.y * xq;
                    acc[2][q] += wv.z * xq;
                    acc[3][q] += wv.w * xq;
                }
            }
        }
        __syncthreads();
    }
    float* yj = j ? y2 : y1;
    #pragma unroll
    for (int o = 0; o < 4; ++o) {
        float sh = shiftA[j * 64 + co0 + o];
        #pragma unroll
        for (int q = 0; q < 4; ++q) {
            float yv = acc[o][q] + sh;
            float sg = 1.f / (1.f + __expf(-yv));
            yj[((size_t)b * 64 + co0 + o) * N_ + h * 64 + w0 + q] = yv * sg;
        }
    }
}

// ---------------------------------------------------------------------------
// K2: softmax row stats.
// ---------------------------------------------------------------------------
__global__ __launch_bounds__(256) void softmax_stats_kernel(
    const float* __restrict__ y1, const float* __restrict__ y2,
    float* __restrict__ rowmax, float* __restrict__ rowinv)
{
    __shared__ __align__(16) float y2s[64][64];
    __shared__ __align__(16) float y1s[64][64];
    __shared__ float red[64][16][2];
    int b  = blockIdx.x >> 6;
    int nt = blockIdx.x & 63;
    int n0 = nt * 64;
    int t = threadIdx.x;
    int tn4 = (t >> 4) * 4;
    int tm4 = (t & 15) * 4;

    for (int i = t; i < 4096; i += 256) {
        int k = i >> 6, nn = i & 63;
        y2s[k][nn] = y2[((size_t)b * 64 + k) * N_ + n0 + nn];
    }
    float runmax[4], runsum[4];
    #pragma unroll
    for (int i = 0; i < 4; ++i) { runmax[i] = -3.0e38f; runsum[i] = 0.f; }

    for (int mt = 0; mt < 64; ++mt) {
        __syncthreads();
        for (int i = t; i < 4096; i += 256) {
            int k = i >> 6, mm = i & 63;
            y1s[k][mm] = y1[((size_t)b * 64 + k) * N_ + mt * 64 + mm];
        }
        __syncthreads();
        float cr[4][4] = {};
        #pragma unroll 16
        for (int k = 0; k < 64; ++k) {
            float4 a  = *(const float4*)&y2s[k][tn4];
            float4 bv = *(const float4*)&y1s[k][tm4];
            cr[0][0] += a.x*bv.x; cr[0][1] += a.x*bv.y; cr[0][2] += a.x*bv.z; cr[0][3] += a.x*bv.w;
            cr[1][0] += a.y*bv.x; cr[1][1] += a.y*bv.y; cr[1][2] += a.y*bv.z; cr[1][3] += a.y*bv.w;
            cr[2][0] += a.z*bv.x; cr[2][1] += a.z*bv.y; cr[2][2] += a.z*bv.z; cr[2][3] += a.z*bv.w;
            cr[3][0] += a.w*bv.x; cr[3][1] += a.w*bv.y; cr[3][2] += a.w*bv.z; cr[3][3] += a.w*bv.w;
        }
        #pragma unroll
        for (int i = 0; i < 4; ++i) {
            float mx = fmaxf(fmaxf(cr[i][0], cr[i][1]), fmaxf(cr[i][2], cr[i][3]));
            float M  = fmaxf(runmax[i], mx);
            float sc = __expf(runmax[i] - M);
            float s  = __expf(cr[i][0] - M) + __expf(cr[i][1] - M)
                     + __expf(cr[i][2] - M) + __expf(cr[i][3] - M);
            runsum[i] = runsum[i] * sc + s;
            runmax[i] = M;
        }
    }
    int tm = t & 15;
    #pragma unroll
    for (int i = 0; i < 4; ++i) {
        red[tn4 + i][tm][0] = runmax[i];
        red[tn4 + i][tm][1] = runsum[i];
    }
    __syncthreads();
    if (t < 64) {
        float M = -3.0e38f;
        #pragma unroll
        for (int q = 0; q < 16; ++q) M = fmaxf(M, red[t][q][0]);
        float S = 0.f;
        #pragma unroll
        for (int q = 0; q < 16; ++q) S += red[t][q][1] * __expf(red[t][q][0] - M);
        rowmax[b * N_ + n0 + t] = M;
        rowinv[b * N_ + n0 + t] = 1.f / S;
    }
}

// ---------------------------------------------------------------------------
// K3: materialize cw = exp(c - rowmax)*rowinv as fp16, TRANSPOSED: cwt[b][m][n].
// ---------------------------------------------------------------------------
__global__ __launch_bounds__(256, 2) void cw_kernel(
    const float* __restrict__ y1, const float* __restrict__ y2,
    const float* __restrict__ rowmax, const float* __restrict__ rowinv,
    u16* __restrict__ cwt)
{
    __shared__ __align__(16) float y2s[64][128];   // [k][n]
    __shared__ __align__(16) float y1s[64][128];   // [k][m]
    int blk = blockIdx.x;
    int mt = blk & 31;
    int nt = (blk >> 5) & 31;
    int b  = blk >> 10;
    int n0 = nt * 128;
    int m0 = mt * 128;
    int t = threadIdx.x;
    int tn8  = (t >> 4) * 8;       // n base (8 rows)
    int tm4a = (t & 15) * 4;       // m group A: tm4a..+3 ; group B: 64+tm4a..+3

    for (int i = t; i < 2048; i += 256) {
        int k = i >> 5, q = (i & 31) * 4;
        *(float4*)&y2s[k][q] = *(const float4*)&y2[((size_t)b * 64 + k) * N_ + n0 + q];
        *(float4*)&y1s[k][q] = *(const float4*)&y1[((size_t)b * 64 + k) * N_ + m0 + q];
    }
    float Mn[8], ivn[8];
    #pragma unroll
    for (int i = 0; i < 8; ++i) {
        Mn[i]  = rowmax[b * N_ + n0 + tn8 + i];
        ivn[i] = rowinv[b * N_ + n0 + tn8 + i];
    }
    __syncthreads();

    float cr[8][8] = {};
    for (int k = 0; k < 64; ++k) {
        float4 a0 = *(const float4*)&y2s[k][tn8];
        float4 a1 = *(const float4*)&y2s[k][tn8 + 4];
        float4 b0 = *(const float4*)&y1s[k][tm4a];
        float4 b1 = *(const float4*)&y1s[k][64 + tm4a];
        float av[8] = {a0.x, a0.y, a0.z, a0.w, a1.x, a1.y, a1.z, a1.w};
        float bv[8] = {b0.x, b0.y, b0.z, b0.w, b1.x, b1.y, b1.z, b1.w};
        #pragma unroll
        for (int i = 0; i < 8; ++i)
            #pragma unroll
            for (int j = 0; j < 8; ++j)
                cr[i][j] += av[i] * bv[j];
    }
    #pragma unroll
    for (int j = 0; j < 8; ++j) {
        int m = (j < 4) ? (tm4a + j) : (64 + tm4a + (j - 4));
        half8 p;
        #pragma unroll
        for (int i = 0; i < 8; ++i)
            p[i] = (_Float16)(__expf(cr[i][j] - Mn[i]) * ivn[i]);
        *(half8*)(void*)(cwt + ((size_t)(b * N_ + m0 + m)) * N_ + n0 + tn8) = p;
    }
}

// ---------------------------------------------------------------------------
// K4: out[b][c][m] = sum_n x[c][n]*cw[n][m] via fp16 MFMA, no LDS.
// ---------------------------------------------------------------------------
__global__ __launch_bounds__(512, 4) void gemm_out_kernel(
    const u16* __restrict__ xh, const u16* __restrict__ cwt, float* __restrict__ out)
{
    int blk = blockIdx.x;
    int mt = blk & 127;
    int b  = blk >> 7;
    int m0 = mt * 32;
    int t = threadIdx.x;
    int lane = t & 63;
    int wv = t >> 6;
    int l16 = lane & 15;
    int kk  = lane >> 4;

    f32x4 acc[4][2] = {};
    const u16* apos = xh + (size_t)b * C_ * N_ + (size_t)(wv * 64 + l16) * N_ + kk * 8;
    const u16* bpos = cwt + (size_t)b * N_ * N_ + (size_t)(m0 + l16) * N_ + kk * 8;

    #pragma unroll 2
    for (int nt = 0; nt < 128; ++nt) {
        int n2 = nt * 32;
        half8 a[4], bb[2];
        #pragma unroll
        for (int ci = 0; ci < 4; ++ci)
            a[ci] = *(const half8*)(const void*)(apos + (size_t)ci * 16 * N_ + n2);
        #pragma unroll
        for (int mi = 0; mi < 2; ++mi)
            bb[mi] = *(const half8*)(const void*)(bpos + (size_t)mi * 16 * N_ + n2);
        #pragma unroll
        for (int ci = 0; ci < 4; ++ci)
            #pragma unroll
            for (int mi = 0; mi < 2; ++mi)
                acc[ci][mi] = __builtin_amdgcn_mfma_f32_16x16x32_f16(a[ci], bb[mi], acc[ci][mi], 0, 0, 0);
    }
    #pragma unroll
    for (int ci = 0; ci < 4; ++ci)
        #pragma unroll
        for (int mi = 0; mi < 2; ++mi)
            #pragma unroll
            for (int r = 0; r < 4; ++r)
                out[((size_t)(b * C_ + wv * 64 + ci * 16 + kk * 4 + r)) * N_ + m0 + mi * 16 + l16]
                    = acc[ci][mi][r];
}

// ---------------------------------------------------------------------------
// Fallback (round-1) attn_out kernel, used only if ws is too small.
// ---------------------------------------------------------------------------
__global__ __launch_bounds__(512) void attn_out_kernel(
    const float* __restrict__ x, const float* __restrict__ y1, const float* __restrict__ y2,
    const float* __restrict__ rowmax, const float* __restrict__ rowinv,
    float* __restrict__ out)
{
    __shared__ __align__(16) float y1s[64][128];
    __shared__ __align__(16) float y2s[64][32];
    __shared__ __align__(16) float cwS[32][128];
    __shared__ __align__(16) float xsm[32][132];
    int blk = blockIdx.x;
    int mb = blk & 31;
    int cb = (blk >> 5) & 3;
    int b  = blk >> 7;
    int m0 = mb * 128;
    int c0 = cb * 128;
    int t = threadIdx.x;
    int tcg8 = (t >> 5) * 8;
    int tmg4 = (t & 31) * 4;
    int cn  = t >> 4;
    int cmq = (t & 15) * 8;

    for (int i = t; i < 64 * 128; i += 512) {
        int k = i >> 7, mm = i & 127;
        y1s[k][mm] = y1[((size_t)b * 64 + k) * N_ + m0 + mm];
    }
    float acc[8][4] = {};
    const float* xb = x + ((size_t)b * C_ + c0) * N_;

    for (int nt = 0; nt < 128; ++nt) {
        int n0 = nt * 32;
        __syncthreads();
        for (int i = t; i < 64 * 32; i += 512) {
            int k = i >> 5, nn = i & 31;
            y2s[k][nn] = y2[((size_t)b * 64 + k) * N_ + n0 + nn];
        }
        for (int i = t; i < 128 * 32; i += 512) {
            int c = i >> 5, nn = i & 31;
            xsm[nn][c] = xb[(size_t)c * N_ + n0 + nn];
        }
        __syncthreads();
        {
            float ca[8] = {};
            #pragma unroll 8
            for (int k = 0; k < 64; ++k) {
                float a   = y2s[k][cn];
                float4 b0 = *(const float4*)&y1s[k][cmq];
                float4 b1 = *(const float4*)&y1s[k][cmq + 4];
                ca[0] += a * b0.x; ca[1] += a * b0.y; ca[2] += a * b0.z; ca[3] += a * b0.w;
                ca[4] += a * b1.x; ca[5] += a * b1.y; ca[6] += a * b1.z; ca[7] += a * b1.w;
            }
            float Mn = rowmax[b * N_ + n0 + cn];
            float iv = rowinv[b * N_ + n0 + cn];
            float4 e0 = make_float4(__expf(ca[0]-Mn)*iv, __expf(ca[1]-Mn)*iv,
                                    __expf(ca[2]-Mn)*iv, __expf(ca[3]-Mn)*iv);
            float4 e1 = make_float4(__expf(ca[4]-Mn)*iv, __expf(ca[5]-Mn)*iv,
                                    __expf(ca[6]-Mn)*iv, __expf(ca[7]-Mn)*iv);
            *(float4*)&cwS[cn][cmq]     = e0;
            *(float4*)&cwS[cn][cmq + 4] = e1;
        }
        __syncthreads();
        #pragma unroll 4
        for (int nn = 0; nn < 32; ++nn) {
            float4 xa = *(const float4*)&xsm[nn][tcg8];
            float4 xc = *(const float4*)&xsm[nn][tcg8 + 4];
            float4 wv = *(const float4*)&cwS[nn][tmg4];
            acc[0][0] += xa.x*wv.x; acc[0][1] += xa.x*wv.y; acc[0][2] += xa.x*wv.z; acc[0][3] += xa.x*wv.w;
            acc[1][0] += xa.y*wv.x; acc[1][1] += xa.y*wv.y; acc[1][2] += xa.y*wv.z; acc[1][3] += xa.y*wv.w;
            acc[2][0] += xa.z*wv.x; acc[2][1] += xa.z*wv.y; acc[2][2] += xa.z*wv.z; acc[2][3] += xa.z*wv.w;
            acc[3][0] += xa.w*wv.x; acc[3][1] += xa.w*wv.y; acc[3][2] += xa.w*wv.z; acc[3][3] += xa.w*wv.w;
            acc[4][0] += xc.x*wv.x; acc[4][1] += xc.x*wv.y; acc[4][2] += xc.x*wv.z; acc[4][3] += xc.x*wv.w;
            acc[5][0] += xc.y*wv.x; acc[5][1] += xc.y*wv.y; acc[5][2] += xc.y*wv.z; acc[5][3] += xc.y*wv.w;
            acc[6][0] += xc.z*wv.x; acc[6][1] += xc.z*wv.y; acc[6][2] += xc.z*wv.z; acc[6][3] += xc.z*wv.w;
            acc[7][0] += xc.w*wv.x; acc[7][1] += xc.w*wv.y; acc[7][2] += xc.w*wv.z; acc[7][3] += xc.w*wv.w;
        }
    }
    #pragma unroll
    for (int q = 0; q < 8; ++q) {
        size_t row = (size_t)b * C_ + c0 + tcg8 + q;
        float4 o4 = make_float4(acc[q][0], acc[q][1], acc[q][2], acc[q][3]);
        *(float4*)&out[row * N_ + m0 + tmg4] = o4;
    }
}

// ---------------------------------------------------------------------------
extern "C" void kernel_launch(void* const* d_in, const int* in_sizes, int n_in,
                              void* d_out, int out_size, void* d_ws, size_t ws_size,
                              hipStream_t stream) {
    const float* x  = (const float*)d_in[0];
    const float* w1 = (const float*)d_in[1];
    const float* g1 = (const float*)d_in[2];
    const float* b1 = (const float*)d_in[3];
    const float* m1 = (const float*)d_in[4];
    const float* v1 = (const float*)d_in[5];
    const float* w2 = (const float*)d_in[6];
    const float* g2 = (const float*)d_in[7];
    const float* b2 = (const float*)d_in[8];
    const float* m2 = (const float*)d_in[9];
    const float* v2 = (const float*)d_in[10];
    float* out = (float*)d_out;

    // Workspace layout — computed, not hand-added (round-2 bug: off-by-204 overlap
    // of xh onto rowinv tail).
    constexpr size_t WT_N     = 2ULL * C_ * 9 * CK_;   // 589824
    constexpr size_t SHIFT_N  = 2ULL * CK_;            // 128
    constexpr size_t Y_N      = (size_t)B_ * CK_ * N_; // 524288
    constexpr size_t ROW_N    = (size_t)B_ * N_;       // 8192
    constexpr size_t XH_N     = (size_t)B_ * C_ * N_;  // 4194304
    constexpr size_t CWT_N    = (size_t)B_ * N_ * N_;  // 33554432

    float* ws = (float*)d_ws;
    float* wT     = ws;
    float* shiftA = wT + WT_N;
    float* y1     = shiftA + SHIFT_N;
    float* y2     = y1 + Y_N;
    float* rowmax = y2 + Y_N;
    float* rowinv = rowmax + ROW_N;
    float* f32_end = rowinv + ROW_N;
    u16*   xh     = (u16*)f32_end;
    u16*   cwt    = xh + XH_N;
    const size_t need_bytes = (size_t)((char*)(cwt + CWT_N) - (char*)d_ws);

    prep_weights_kernel<<<2304, 256, 0, stream>>>(w1, g1, b1, m1, v1,
                                                  w2, g2, b2, m2, v2, wT, shiftA);
    conv_bn_silu_kernel<<<256, 256, 0, stream>>>(x, wT, shiftA, y1, y2);
    softmax_stats_kernel<<<128, 256, 0, stream>>>(y1, y2, rowmax, rowinv);

    if (ws_size >= need_bytes) {
        cast_x_kernel<<<2048, 256, 0, stream>>>(x, xh);
        cw_kernel<<<2048, 256, 0, stream>>>(y1, y2, rowmax, rowinv, cwt);
        gemm_out_kernel<<<256, 512, 0, stream>>>(xh, cwt, out);
    } else {
        attn_out_kernel<<<256, 512, 0, stream>>>(x, y1, y2, rowmax, rowinv, out);
    }
}

// Round 6
// 662.282 us; speedup vs baseline: 3.0624x; 1.6896x over previous
//
#include <hip/hip_runtime.h>

#define BN_EPS 1e-5f
#define B_ 2
#define C_ 512
#define CK_ 64
#define N_ 4096

typedef unsigned short u16;
typedef _Float16 half8 __attribute__((ext_vector_type(8)));
typedef _Float16 half4 __attribute__((ext_vector_type(4)));
typedef float f32x4 __attribute__((ext_vector_type(4)));

// ---------------------------------------------------------------------------
// K0: fold BN scale into conv weights, transpose to [j][c][tap][co]; shift[j][co]
// ---------------------------------------------------------------------------
__global__ __launch_bounds__(256) void prep_weights_kernel(
    const float* __restrict__ w1, const float* __restrict__ g1, const float* __restrict__ b1,
    const float* __restrict__ m1, const float* __restrict__ v1,
    const float* __restrict__ w2, const float* __restrict__ g2, const float* __restrict__ b2,
    const float* __restrict__ m2, const float* __restrict__ v2,
    float* __restrict__ wT, float* __restrict__ shiftA)
{
    int idx = blockIdx.x * 256 + threadIdx.x;
    const int total = 2 * C_ * 9 * CK_;
    if (idx < total) {
        int co = idx & 63;
        int t9 = (idx >> 6) % 9;
        int c  = (idx / (9 * 64)) % C_;
        int j  = idx / (9 * 64 * C_);
        const float* w = j ? w2 : w1;
        const float* g = j ? g2 : g1;
        const float* v = j ? v2 : v1;
        float scale = g[co] / sqrtf(v[co] + BN_EPS);
        wT[idx] = w[((size_t)co * C_ + c) * 9 + t9] * scale;
    }
    if (idx < 2 * CK_) {
        int j = idx >> 6, co = idx & 63;
        const float* g = j ? g2 : g1;
        const float* v = j ? v2 : v1;
        const float* bb = j ? b2 : b1;
        const float* mm = j ? m2 : m1;
        float scale = g[co] / sqrtf(v[co] + BN_EPS);
        shiftA[idx] = bb[co] - mm[co] * scale;
    }
}

// ---------------------------------------------------------------------------
// K0b: cast x (fp32) -> fp16, same [b][c][n] layout
// ---------------------------------------------------------------------------
__global__ __launch_bounds__(256) void cast_x_kernel(
    const float* __restrict__ x, u16* __restrict__ xh)
{
    int i = (blockIdx.x * 256 + threadIdx.x) * 8;
    float4 v0 = *(const float4*)(x + i);
    float4 v1 = *(const float4*)(x + i + 4);
    half8 h;
    h[0] = (_Float16)v0.x; h[1] = (_Float16)v0.y; h[2] = (_Float16)v0.z; h[3] = (_Float16)v0.w;
    h[4] = (_Float16)v1.x; h[5] = (_Float16)v1.y; h[6] = (_Float16)v1.z; h[7] = (_Float16)v1.w;
    *(half8*)(void*)(xh + i) = h;
}

// ---------------------------------------------------------------------------
// K1: conv3x3 + BN(shift) + SiLU (unchanged; next round's target).
// ---------------------------------------------------------------------------
__global__ __launch_bounds__(256) void conv_bn_silu_kernel(
    const float* __restrict__ x, const float* __restrict__ wT,
    const float* __restrict__ shiftA, float* __restrict__ y1, float* __restrict__ y2)
{
    __shared__ float xs[8][3][66];
    __shared__ __align__(16) float ws[8 * 9 * 64];
    int blk = blockIdx.x;
    int h = blk & 63;
    int j = (blk >> 6) & 1;
    int b = blk >> 7;
    int t = threadIdx.x;
    int w0  = (t & 15) * 4;
    int co0 = (t >> 4) * 4;
    float acc[4][4] = {};
    const float* xb = x + (size_t)b * C_ * N_;
    const float* wj = wT + (size_t)j * C_ * 9 * 64;

    for (int cc = 0; cc < C_ / 8; ++cc) {
        for (int i = t; i < 8 * 3 * 64; i += 256) {
            int c = i / 192;
            int r = (i / 64) % 3;
            int ww = i & 63;
            int row = h - 1 + r;
            float val = 0.f;
            if (row >= 0 && row < 64)
                val = xb[((size_t)(cc * 8 + c) * 64 + row) * 64 + ww];
            xs[c][r][ww + 1] = val;
        }
        if (t < 24) {
            int c = t / 3, r = t - c * 3;
            xs[c][r][0]  = 0.f;
            xs[c][r][65] = 0.f;
        }
        {
            const float4* src = (const float4*)(wj + cc * 4608);
            float4* dst = (float4*)ws;
            for (int i = t; i < 1152; i += 256) dst[i] = src[i];
        }
        __syncthreads();
        #pragma unroll
        for (int c = 0; c < 8; ++c) {
            float xv[3][6];
            #pragma unroll
            for (int r = 0; r < 3; ++r)
                #pragma unroll
                for (int q = 0; q < 6; ++q)
                    xv[r][q] = xs[c][r][w0 + q];
            #pragma unroll
            for (int tap = 0; tap < 9; ++tap) {
                int dh = tap / 3, dw = tap - dh * 3;
                float4 wv = *(const float4*)&ws[(c * 9 + tap) * 64 + co0];
                #pragma unroll
                for (int q = 0; q < 4; ++q) {
                    float xq = xv[dh][q + dw];
                    acc[0][q] += wv.x * xq;
                    acc[1][q] += wv.y * xq;
                    acc[2][q] += wv.z * xq;
                    acc[3][q] += wv.w * xq;
                }
            }
        }
        __syncthreads();
    }
    float* yj = j ? y2 : y1;
    #pragma unroll
    for (int o = 0; o < 4; ++o) {
        float sh = shiftA[j * 64 + co0 + o];
        #pragma unroll
        for (int q = 0; q < 4; ++q) {
            float yv = acc[o][q] + sh;
            float sg = 1.f / (1.f + __expf(-yv));
            yj[((size_t)b * 64 + co0 + o) * N_ + h * 64 + w0 + q] = yv * sg;
        }
    }
}

// ---------------------------------------------------------------------------
// K1b: transpose y [b][k][n] fp32 -> yt [b][n][64] fp16. One thread per n-row.
// ---------------------------------------------------------------------------
__global__ __launch_bounds__(256) void transpose_y_kernel(
    const float* __restrict__ y1, const float* __restrict__ y2,
    u16* __restrict__ y1t, u16* __restrict__ y2t)
{
    int id = blockIdx.x * 256 + threadIdx.x;     // 2 * B * N = 16384
    bool first = id < B_ * N_;
    int r = first ? id : id - B_ * N_;
    const float* src = first ? y1 : y2;
    u16* dst = first ? y1t : y2t;
    int b = r >> 12, n = r & 4095;
    const float* sp = src + (size_t)b * CK_ * N_ + n;
    u16* dp = dst + ((size_t)b * N_ + n) * CK_;
    #pragma unroll
    for (int kc = 0; kc < 8; ++kc) {
        half8 h;
        #pragma unroll
        for (int q = 0; q < 8; ++q)
            h[q] = (_Float16)sp[(size_t)(kc * 8 + q) * N_];
        *(half8*)(void*)(dp + kc * 8) = h;
    }
}

// ---------------------------------------------------------------------------
// K2: softmax stats via MFMA.  Grid = B * 64 ntiles * 4 mchunks = 512 blocks.
// Wave w owns n-rows nw..nw+15; sweeps 1024 m; online (max,sum) per row.
// c chain: acc = mfma(a1, b1, mfma(a0, b0, 0)) — identical in cw_mfma_kernel.
// ---------------------------------------------------------------------------
__global__ __launch_bounds__(256) void stats_mfma_kernel(
    const u16* __restrict__ y1t, const u16* __restrict__ y2t,
    float* __restrict__ part)   // part[b][4][n][2]
{
    int blk = blockIdx.x;
    int mc = blk & 3;
    int nt = (blk >> 2) & 63;
    int b  = blk >> 8;
    int n0 = nt * 64;
    int t = threadIdx.x;
    int w = t >> 6, lane = t & 63;
    int l16 = lane & 15, kk = lane >> 4;
    const u16* yt1b = y1t + (size_t)b * N_ * CK_;
    const u16* yt2b = y2t + (size_t)b * N_ * CK_;

    int nw = n0 + w * 16;
    const u16* ap = yt2b + (size_t)(nw + l16) * CK_ + kk * 8;
    half8 a0 = *(const half8*)(const void*)ap;
    half8 a1 = *(const half8*)(const void*)(ap + 32);

    float rmax[4] = {-3.0e38f, -3.0e38f, -3.0e38f, -3.0e38f};
    float rsum[4] = {0.f, 0.f, 0.f, 0.f};
    int mbase = mc * 1024;

    for (int mi = 0; mi < 16; ++mi) {
        int m0 = mbase + mi * 64;
        #pragma unroll
        for (int ms = 0; ms < 4; ++ms) {
            const u16* bp = yt1b + (size_t)(m0 + ms * 16 + l16) * CK_ + kk * 8;
            half8 b0 = *(const half8*)(const void*)bp;
            half8 b1 = *(const half8*)(const void*)(bp + 32);
            f32x4 acc = {0.f, 0.f, 0.f, 0.f};
            acc = __builtin_amdgcn_mfma_f32_16x16x32_f16(a0, b0, acc, 0, 0, 0);
            acc = __builtin_amdgcn_mfma_f32_16x16x32_f16(a1, b1, acc, 0, 0, 0);
            #pragma unroll
            for (int r = 0; r < 4; ++r) {
                float c = acc[r];
                float M = fmaxf(rmax[r], c);
                rsum[r] = rsum[r] * __expf(rmax[r] - M) + __expf(c - M);
                rmax[r] = M;
            }
        }
    }
    // reduce across the 16 column lanes (same kk group)
    #pragma unroll
    for (int r = 0; r < 4; ++r) {
        float M = rmax[r], S = rsum[r];
        #pragma unroll
        for (int d = 1; d < 16; d <<= 1) {
            float Mo = __shfl_xor(M, d, 64);
            float So = __shfl_xor(S, d, 64);
            float Mn = fmaxf(M, Mo);
            S = S * __expf(M - Mn) + So * __expf(Mo - Mn);
            M = Mn;
        }
        if (l16 == 0) {
            int n = nw + kk * 4 + r;
            size_t o = (((size_t)b * 4 + mc) * N_ + n) * 2;
            part[o]     = M;
            part[o + 1] = S;
        }
    }
}

__global__ __launch_bounds__(256) void stats_final_kernel(
    const float* __restrict__ part, float* __restrict__ rowmax, float* __restrict__ rowinv)
{
    int i = blockIdx.x * 256 + threadIdx.x;   // B*N = 8192
    if (i >= B_ * N_) return;
    int b = i / N_, n = i % N_;
    float M = -3.0e38f, S = 0.f;
    #pragma unroll
    for (int c = 0; c < 4; ++c) {
        size_t o = (((size_t)b * 4 + c) * N_ + n) * 2;
        float Mc = part[o], Sc = part[o + 1];
        float Mn = fmaxf(M, Mc);
        S = S * __expf(M - Mn) + Sc * __expf(Mc - Mn);
        M = Mn;
    }
    rowmax[i] = M;
    rowinv[i] = 1.f / S;
}

// ---------------------------------------------------------------------------
// K3: cw via MFMA, identical c chain to stats.  Grid = B*64nt*16mt = 2048.
// Wave w owns m-range m0+w*64; computes 64n x 64m; stores half4 to cwt[m][n].
// ---------------------------------------------------------------------------
__global__ __launch_bounds__(256) void cw_mfma_kernel(
    const u16* __restrict__ y1t, const u16* __restrict__ y2t,
    const float* __restrict__ rowmax, const float* __restrict__ rowinv,
    u16* __restrict__ cwt)
{
    __shared__ float Ms[64], Ivs[64];
    int blk = blockIdx.x;
    int mt = blk & 15;
    int nt = (blk >> 4) & 63;
    int b  = blk >> 10;
    int n0 = nt * 64, m0 = mt * 256;
    int t = threadIdx.x;
    int w = t >> 6, lane = t & 63;
    int l16 = lane & 15, kk = lane >> 4;
    if (t < 64) {
        Ms[t]  = rowmax[b * N_ + n0 + t];
        Ivs[t] = rowinv[b * N_ + n0 + t];
    }
    const u16* yt1b = y1t + (size_t)b * N_ * CK_;
    const u16* yt2b = y2t + (size_t)b * N_ * CK_;

    half8 A0[4], A1[4];
    #pragma unroll
    for (int ns = 0; ns < 4; ++ns) {
        const u16* ap = yt2b + (size_t)(n0 + ns * 16 + l16) * CK_ + kk * 8;
        A0[ns] = *(const half8*)(const void*)ap;
        A1[ns] = *(const half8*)(const void*)(ap + 32);
    }
    __syncthreads();

    int mw = m0 + w * 64;
    #pragma unroll
    for (int ms = 0; ms < 4; ++ms) {
        const u16* bp = yt1b + (size_t)(mw + ms * 16 + l16) * CK_ + kk * 8;
        half8 B0 = *(const half8*)(const void*)bp;
        half8 B1 = *(const half8*)(const void*)(bp + 32);
        int m = mw + ms * 16 + l16;
        u16* orow = cwt + ((size_t)(b * N_ + m)) * N_ + n0;
        #pragma unroll
        for (int ns = 0; ns < 4; ++ns) {
            f32x4 acc = {0.f, 0.f, 0.f, 0.f};
            acc = __builtin_amdgcn_mfma_f32_16x16x32_f16(A0[ns], B0, acc, 0, 0, 0);
            acc = __builtin_amdgcn_mfma_f32_16x16x32_f16(A1[ns], B1, acc, 0, 0, 0);
            int nl = ns * 16 + kk * 4;
            half4 p;
            #pragma unroll
            for (int r = 0; r < 4; ++r)
                p[r] = (_Float16)(__expf(acc[r] - Ms[nl + r]) * Ivs[nl + r]);
            *(half4*)(void*)(orow + nl) = p;
        }
    }
}

// ---------------------------------------------------------------------------
// K4: out[b][c][m] = sum_n x[c][n]*cw[n][m] via fp16 MFMA (validated r4).
// ---------------------------------------------------------------------------
__global__ __launch_bounds__(512, 4) void gemm_out_kernel(
    const u16* __restrict__ xh, const u16* __restrict__ cwt, float* __restrict__ out)
{
    int blk = blockIdx.x;
    int mt = blk & 127;
    int b  = blk >> 7;
    int m0 = mt * 32;
    int t = threadIdx.x;
    int lane = t & 63;
    int wv = t >> 6;
    int l16 = lane & 15;
    int kk  = lane >> 4;

    f32x4 acc[4][2] = {};
    const u16* apos = xh + (size_t)b * C_ * N_ + (size_t)(wv * 64 + l16) * N_ + kk * 8;
    const u16* bpos = cwt + (size_t)b * N_ * N_ + (size_t)(m0 + l16) * N_ + kk * 8;

    #pragma unroll 2
    for (int nt = 0; nt < 128; ++nt) {
        int n2 = nt * 32;
        half8 a[4], bb[2];
        #pragma unroll
        for (int ci = 0; ci < 4; ++ci)
            a[ci] = *(const half8*)(const void*)(apos + (size_t)ci * 16 * N_ + n2);
        #pragma unroll
        for (int mi = 0; mi < 2; ++mi)
            bb[mi] = *(const half8*)(const void*)(bpos + (size_t)mi * 16 * N_ + n2);
        #pragma unroll
        for (int ci = 0; ci < 4; ++ci)
            #pragma unroll
            for (int mi = 0; mi < 2; ++mi)
                acc[ci][mi] = __builtin_amdgcn_mfma_f32_16x16x32_f16(a[ci], bb[mi], acc[ci][mi], 0, 0, 0);
    }
    #pragma unroll
    for (int ci = 0; ci < 4; ++ci)
        #pragma unroll
        for (int mi = 0; mi < 2; ++mi)
            #pragma unroll
            for (int r = 0; r < 4; ++r)
                out[((size_t)(b * C_ + wv * 64 + ci * 16 + kk * 4 + r)) * N_ + m0 + mi * 16 + l16]
                    = acc[ci][mi][r];
}

// ---------------------------------------------------------------------------
// Fallback fp32 stats + attn_out (used only if ws too small).
// ---------------------------------------------------------------------------
__global__ __launch_bounds__(256) void softmax_stats_kernel(
    const float* __restrict__ y1, const float* __restrict__ y2,
    float* __restrict__ rowmax, float* __restrict__ rowinv)
{
    __shared__ __align__(16) float y2s[64][64];
    __shared__ __align__(16) float y1s[64][64];
    __shared__ float red[64][16][2];
    int b  = blockIdx.x >> 6;
    int nt = blockIdx.x & 63;
    int n0 = nt * 64;
    int t = threadIdx.x;
    int tn4 = (t >> 4) * 4;
    int tm4 = (t & 15) * 4;

    for (int i = t; i < 4096; i += 256) {
        int k = i >> 6, nn = i & 63;
        y2s[k][nn] = y2[((size_t)b * 64 + k) * N_ + n0 + nn];
    }
    float runmax[4], runsum[4];
    #pragma unroll
    for (int i = 0; i < 4; ++i) { runmax[i] = -3.0e38f; runsum[i] = 0.f; }

    for (int mt = 0; mt < 64; ++mt) {
        __syncthreads();
        for (int i = t; i < 4096; i += 256) {
            int k = i >> 6, mm = i & 63;
            y1s[k][mm] = y1[((size_t)b * 64 + k) * N_ + mt * 64 + mm];
        }
        __syncthreads();
        float cr[4][4] = {};
        #pragma unroll 16
        for (int k = 0; k < 64; ++k) {
            float4 a  = *(const float4*)&y2s[k][tn4];
            float4 bv = *(const float4*)&y1s[k][tm4];
            cr[0][0] += a.x*bv.x; cr[0][1] += a.x*bv.y; cr[0][2] += a.x*bv.z; cr[0][3] += a.x*bv.w;
            cr[1][0] += a.y*bv.x; cr[1][1] += a.y*bv.y; cr[1][2] += a.y*bv.z; cr[1][3] += a.y*bv.w;
            cr[2][0] += a.z*bv.x; cr[2][1] += a.z*bv.y; cr[2][2] += a.z*bv.z; cr[2][3] += a.z*bv.w;
            cr[3][0] += a.w*bv.x; cr[3][1] += a.w*bv.y; cr[3][2] += a.w*bv.z; cr[3][3] += a.w*bv.w;
        }
        #pragma unroll
        for (int i = 0; i < 4; ++i) {
            float mx = fmaxf(fmaxf(cr[i][0], cr[i][1]), fmaxf(cr[i][2], cr[i][3]));
            float M  = fmaxf(runmax[i], mx);
            float sc = __expf(runmax[i] - M);
            float s  = __expf(cr[i][0] - M) + __expf(cr[i][1] - M)
                     + __expf(cr[i][2] - M) + __expf(cr[i][3] - M);
            runsum[i] = runsum[i] * sc + s;
            runmax[i] = M;
        }
    }
    int tm = t & 15;
    #pragma unroll
    for (int i = 0; i < 4; ++i) {
        red[tn4 + i][tm][0] = runmax[i];
        red[tn4 + i][tm][1] = runsum[i];
    }
    __syncthreads();
    if (t < 64) {
        float M = -3.0e38f;
        #pragma unroll
        for (int q = 0; q < 16; ++q) M = fmaxf(M, red[t][q][0]);
        float S = 0.f;
        #pragma unroll
        for (int q = 0; q < 16; ++q) S += red[t][q][1] * __expf(red[t][q][0] - M);
        rowmax[b * N_ + n0 + t] = M;
        rowinv[b * N_ + n0 + t] = 1.f / S;
    }
}

__global__ __launch_bounds__(512) void attn_out_kernel(
    const float* __restrict__ x, const float* __restrict__ y1, const float* __restrict__ y2,
    const float* __restrict__ rowmax, const float* __restrict__ rowinv,
    float* __restrict__ out)
{
    __shared__ __align__(16) float y1s[64][128];
    __shared__ __align__(16) float y2s[64][32];
    __shared__ __align__(16) float cwS[32][128];
    __shared__ __align__(16) float xsm[32][132];
    int blk = blockIdx.x;
    int mb = blk & 31;
    int cb = (blk >> 5) & 3;
    int b  = blk >> 7;
    int m0 = mb * 128;
    int c0 = cb * 128;
    int t = threadIdx.x;
    int tcg8 = (t >> 5) * 8;
    int tmg4 = (t & 31) * 4;
    int cn  = t >> 4;
    int cmq = (t & 15) * 8;

    for (int i = t; i < 64 * 128; i += 512) {
        int k = i >> 7, mm = i & 127;
        y1s[k][mm] = y1[((size_t)b * 64 + k) * N_ + m0 + mm];
    }
    float acc[8][4] = {};
    const float* xb = x + ((size_t)b * C_ + c0) * N_;

    for (int nt = 0; nt < 128; ++nt) {
        int n0 = nt * 32;
        __syncthreads();
        for (int i = t; i < 64 * 32; i += 512) {
            int k = i >> 5, nn = i & 31;
            y2s[k][nn] = y2[((size_t)b * 64 + k) * N_ + n0 + nn];
        }
        for (int i = t; i < 128 * 32; i += 512) {
            int c = i >> 5, nn = i & 31;
            xsm[nn][c] = xb[(size_t)c * N_ + n0 + nn];
        }
        __syncthreads();
        {
            float ca[8] = {};
            #pragma unroll 8
            for (int k = 0; k < 64; ++k) {
                float a   = y2s[k][cn];
                float4 b0 = *(const float4*)&y1s[k][cmq];
                float4 b1 = *(const float4*)&y1s[k][cmq + 4];
                ca[0] += a * b0.x; ca[1] += a * b0.y; ca[2] += a * b0.z; ca[3] += a * b0.w;
                ca[4] += a * b1.x; ca[5] += a * b1.y; ca[6] += a * b1.z; ca[7] += a * b1.w;
            }
            float Mn = rowmax[b * N_ + n0 + cn];
            float iv = rowinv[b * N_ + n0 + cn];
            float4 e0 = make_float4(__expf(ca[0]-Mn)*iv, __expf(ca[1]-Mn)*iv,
                                    __expf(ca[2]-Mn)*iv, __expf(ca[3]-Mn)*iv);
            float4 e1 = make_float4(__expf(ca[4]-Mn)*iv, __expf(ca[5]-Mn)*iv,
                                    __expf(ca[6]-Mn)*iv, __expf(ca[7]-Mn)*iv);
            *(float4*)&cwS[cn][cmq]     = e0;
            *(float4*)&cwS[cn][cmq + 4] = e1;
        }
        __syncthreads();
        #pragma unroll 4
        for (int nn = 0; nn < 32; ++nn) {
            float4 xa = *(const float4*)&xsm[nn][tcg8];
            float4 xc = *(const float4*)&xsm[nn][tcg8 + 4];
            float4 wv = *(const float4*)&cwS[nn][tmg4];
            acc[0][0] += xa.x*wv.x; acc[0][1] += xa.x*wv.y; acc[0][2] += xa.x*wv.z; acc[0][3] += xa.x*wv.w;
            acc[1][0] += xa.y*wv.x; acc[1][1] += xa.y*wv.y; acc[1][2] += xa.y*wv.z; acc[1][3] += xa.y*wv.w;
            acc[2][0] += xa.z*wv.x; acc[2][1] += xa.z*wv.y; acc[2][2] += xa.z*wv.z; acc[2][3] += xa.z*wv.w;
            acc[3][0] += xa.w*wv.x; acc[3][1] += xa.w*wv.y; acc[3][2] += xa.w*wv.z; acc[3][3] += xa.w*wv.w;
            acc[4][0] += xc.x*wv.x; acc[4][1] += xc.x*wv.y; acc[4][2] += xc.x*wv.z; acc[4][3] += xc.x*wv.w;
            acc[5][0] += xc.y*wv.x; acc[5][1] += xc.y*wv.y; acc[5][2] += xc.y*wv.z; acc[5][3] += xc.y*wv.w;
            acc[6][0] += xc.z*wv.x; acc[6][1] += xc.z*wv.y; acc[6][2] += xc.z*wv.z; acc[6][3] += xc.z*wv.w;
            acc[7][0] += xc.w*wv.x; acc[7][1] += xc.w*wv.y; acc[7][2] += xc.w*wv.z; acc[7][3] += xc.w*wv.w;
        }
    }
    #pragma unroll
    for (int q = 0; q < 8; ++q) {
        size_t row = (size_t)b * C_ + c0 + tcg8 + q;
        float4 o4 = make_float4(acc[q][0], acc[q][1], acc[q][2], acc[q][3]);
        *(float4*)&out[row * N_ + m0 + tmg4] = o4;
    }
}

// ---------------------------------------------------------------------------
extern "C" void kernel_launch(void* const* d_in, const int* in_sizes, int n_in,
                              void* d_out, int out_size, void* d_ws, size_t ws_size,
                              hipStream_t stream) {
    const float* x  = (const float*)d_in[0];
    const float* w1 = (const float*)d_in[1];
    const float* g1 = (const float*)d_in[2];
    const float* b1 = (const float*)d_in[3];
    const float* m1 = (const float*)d_in[4];
    const float* v1 = (const float*)d_in[5];
    const float* w2 = (const float*)d_in[6];
    const float* g2 = (const float*)d_in[7];
    const float* b2 = (const float*)d_in[8];
    const float* m2 = (const float*)d_in[9];
    const float* v2 = (const float*)d_in[10];
    float* out = (float*)d_out;

    constexpr size_t WT_N    = 2ULL * C_ * 9 * CK_;    // 589824
    constexpr size_t SHIFT_N = 2ULL * CK_;             // 128
    constexpr size_t Y_N     = (size_t)B_ * CK_ * N_;  // 524288
    constexpr size_t ROW_N   = (size_t)B_ * N_;        // 8192
    constexpr size_t PART_N  = (size_t)B_ * 4 * N_ * 2;// 65536
    constexpr size_t XH_N    = (size_t)B_ * C_ * N_;   // 4194304
    constexpr size_t CWT_N   = (size_t)B_ * N_ * N_;   // 33554432
    constexpr size_t YT_N    = (size_t)B_ * N_ * CK_;  // 524288

    float* ws = (float*)d_ws;
    float* wT     = ws;
    float* shiftA = wT + WT_N;
    float* y1     = shiftA + SHIFT_N;
    float* y2     = y1 + Y_N;
    float* rowmax = y2 + Y_N;
    float* rowinv = rowmax + ROW_N;
    float* part   = rowinv + ROW_N;
    float* f32_end = part + PART_N;
    u16*   xh     = (u16*)f32_end;
    u16*   cwt    = xh + XH_N;
    u16*   y1t    = cwt + CWT_N;
    u16*   y2t    = y1t + YT_N;
    const size_t need_bytes = (size_t)((char*)(y2t + YT_N) - (char*)d_ws);

    prep_weights_kernel<<<2304, 256, 0, stream>>>(w1, g1, b1, m1, v1,
                                                  w2, g2, b2, m2, v2, wT, shiftA);
    conv_bn_silu_kernel<<<256, 256, 0, stream>>>(x, wT, shiftA, y1, y2);

    if (ws_size >= need_bytes) {
        cast_x_kernel<<<2048, 256, 0, stream>>>(x, xh);
        transpose_y_kernel<<<64, 256, 0, stream>>>(y1, y2, y1t, y2t);
        stats_mfma_kernel<<<512, 256, 0, stream>>>(y1t, y2t, part);
        stats_final_kernel<<<32, 256, 0, stream>>>(part, rowmax, rowinv);
        cw_mfma_kernel<<<2048, 256, 0, stream>>>(y1t, y2t, rowmax, rowinv, cwt);
        gemm_out_kernel<<<256, 512, 0, stream>>>(xh, cwt, out);
    } else {
        softmax_stats_kernel<<<128, 256, 0, stream>>>(y1, y2, rowmax, rowinv);
        attn_out_kernel<<<256, 512, 0, stream>>>(x, y1, y2, rowmax, rowinv, out);
    }
}

// Round 8
// 369.666 us; speedup vs baseline: 5.4865x; 1.7916x over previous
//
#include <hip/hip_runtime.h>

#define BN_EPS 1e-5f
#define B_ 2
#define C_ 512
#define CK_ 64
#define N_ 4096

typedef unsigned short u16;
typedef _Float16 half8 __attribute__((ext_vector_type(8)));
typedef _Float16 half4 __attribute__((ext_vector_type(4)));
typedef float f32x4 __attribute__((ext_vector_type(4)));

static __device__ inline u16 h2u(_Float16 h) {
    union { _Float16 h; u16 u; } x; x.h = h; return x.u;
}

// ---------------------------------------------------------------------------
// K0: fold BN scale into conv weights -> fp16 wh[j][tap][co][c]; shift[j][co] f32
// ---------------------------------------------------------------------------
__global__ __launch_bounds__(256) void prep_weights_kernel(
    const float* __restrict__ w1, const float* __restrict__ g1, const float* __restrict__ b1,
    const float* __restrict__ m1, const float* __restrict__ v1,
    const float* __restrict__ w2, const float* __restrict__ g2, const float* __restrict__ b2,
    const float* __restrict__ m2, const float* __restrict__ v2,
    u16* __restrict__ wh, float* __restrict__ shiftA)
{
    int idx = blockIdx.x * 256 + threadIdx.x;    // 2*9*64*512 = 589824 exactly
    int c   = idx & 511;
    int co  = (idx >> 9) & 63;
    int tap = (idx >> 15) % 9;
    int j   = idx / (9 << 15);
    const float* w = j ? w2 : w1;
    const float* g = j ? g2 : g1;
    const float* v = j ? v2 : v1;
    float scale = g[co] / sqrtf(v[co] + BN_EPS);
    float val = w[((size_t)co * C_ + c) * 9 + tap] * scale;
    wh[idx] = h2u((_Float16)val);
    if (idx < 2 * CK_) {
        int jj = idx >> 6, cc = idx & 63;
        const float* gg = jj ? g2 : g1;
        const float* vv = jj ? v2 : v1;
        const float* bb = jj ? b2 : b1;
        const float* mm = jj ? m2 : m1;
        float sc = gg[cc] / sqrtf(vv[cc] + BN_EPS);
        shiftA[idx] = bb[cc] - mm[cc] * sc;
    }
}

// ---------------------------------------------------------------------------
// K0b: cast x (fp32) -> fp16 xh, same [b][c][n] layout (gemm_out A operand)
// ---------------------------------------------------------------------------
__global__ __launch_bounds__(256) void cast_x_kernel(
    const float* __restrict__ x, u16* __restrict__ xh)
{
    int i = (blockIdx.x * 256 + threadIdx.x) * 8;
    float4 v0 = *(const float4*)(x + i);
    float4 v1 = *(const float4*)(x + i + 4);
    half8 h;
    h[0] = (_Float16)v0.x; h[1] = (_Float16)v0.y; h[2] = (_Float16)v0.z; h[3] = (_Float16)v0.w;
    h[4] = (_Float16)v1.x; h[5] = (_Float16)v1.y; h[6] = (_Float16)v1.z; h[7] = (_Float16)v1.w;
    *(half8*)(void*)(xh + i) = h;
}

// ---------------------------------------------------------------------------
// K0c: transpose x [b][c][n] f32 -> xt [b][n][512c] fp16 (conv staging source).
// Grid 256: blk -> (b, kg(8 c-groups of 64), nb(16 n-blocks of 256)).
// Reads coalesced across lanes (consecutive n, fixed c).
// ---------------------------------------------------------------------------
__global__ __launch_bounds__(256) void transpose_x_kernel(
    const float* __restrict__ x, u16* __restrict__ xt)
{
    int blk = blockIdx.x;
    int nb = blk & 15;
    int kg = (blk >> 4) & 7;
    int b  = blk >> 7;
    int n = nb * 256 + threadIdx.x;
    const float* sp = x + (size_t)b * C_ * N_ + n;
    u16* dp = xt + ((size_t)(b * N_ + n)) * C_;
    #pragma unroll
    for (int kc = 0; kc < 8; ++kc) {
        int c0 = kg * 64 + kc * 8;
        half8 h;
        #pragma unroll
        for (int q = 0; q < 8; ++q)
            h[q] = (_Float16)sp[(size_t)(c0 + q) * N_];
        *(half8*)(void*)(dp + c0) = h;
    }
}

// ---------------------------------------------------------------------------
// K1: conv3x3 + BN + SiLU via implicit-GEMM MFMA.
// Block = (b, j, h): 64 w x 64 co.  8 waves: wave = 16w x 32co (2 MFMA/K-step).
// K = tap-outer, 32-c chunks (16 chunks).  LDS c-dim padded 32->40 halfs
// (stride 80B -> 8-slot bank spread, 2-way max = free, no swizzle VALU).
// Output: yt[b][n][64co] fp16 (the transposed layout stats/cw consume).
// ---------------------------------------------------------------------------
__global__ __launch_bounds__(512) void conv_mfma_kernel(
    const u16* __restrict__ xt, const u16* __restrict__ wh,
    const float* __restrict__ shiftA,
    u16* __restrict__ y1t, u16* __restrict__ y2t)
{
    __shared__ __align__(16) _Float16 xs[3 * 66 * 40];   // [r][wi][40]
    __shared__ __align__(16) _Float16 wsm[9 * 64 * 40];  // [tap][co][40]
    int blk = blockIdx.x;
    int h = blk & 63;
    int j = (blk >> 6) & 1;
    int b = blk >> 7;
    int t = threadIdx.x;
    int wave = t >> 6, lane = t & 63;
    int l16 = lane & 15, kk = lane >> 4;
    int w0  = (wave & 3) * 16;
    int co0 = (wave >> 2) * 32;

    const u16* xtb = xt + (size_t)b * N_ * C_;
    const u16* whj = wh + (size_t)j * 9 * 64 * C_;

    f32x4 acc[2] = {};

    for (int cc = 0; cc < 16; ++cc) {
        __syncthreads();   // prior-chunk reads done before overwrite
        // stage x: 3 rows x 66 wi x 4 half8 = 792 16B-writes
        for (int i = t; i < 792; i += 512) {
            int c8 = i & 3;
            int wi = (i >> 2) % 66;
            int r  = i / 264;
            int row = h - 1 + r;
            half8 v = {};
            if (row >= 0 && row < 64 && wi >= 1 && wi <= 64)
                v = *(const half8*)(const void*)(xtb
                      + ((size_t)(row * 64 + wi - 1)) * C_ + cc * 32 + c8 * 8);
            *(half8*)(void*)&xs[(r * 66 + wi) * 40 + c8 * 8] = v;
        }
        // stage w: 9 taps x 64 co x 4 half8 = 2304 16B-writes
        for (int i = t; i < 2304; i += 512) {
            int c8 = i & 3;
            int co = (i >> 2) & 63;
            int tap = i >> 8;
            *(half8*)(void*)&wsm[(tap * 64 + co) * 40 + c8 * 8] =
                *(const half8*)(const void*)(whj
                    + ((size_t)(tap * 64 + co)) * C_ + cc * 32 + c8 * 8);
        }
        __syncthreads();
        #pragma unroll
        for (int tap = 0; tap < 9; ++tap) {
            int dh = tap / 3, dw = tap - dh * 3;
            int wi = w0 + l16 + dw;
            half8 a  = *(const half8*)(const void*)&xs[(dh * 66 + wi) * 40 + kk * 8];
            half8 b0 = *(const half8*)(const void*)&wsm[(tap * 64 + co0 + l16) * 40 + kk * 8];
            half8 b1 = *(const half8*)(const void*)&wsm[(tap * 64 + co0 + 16 + l16) * 40 + kk * 8];
            acc[0] = __builtin_amdgcn_mfma_f32_16x16x32_f16(a, b0, acc[0], 0, 0, 0);
            acc[1] = __builtin_amdgcn_mfma_f32_16x16x32_f16(a, b1, acc[1], 0, 0, 0);
        }
    }
    // epilogue: shift + SiLU, store fp16 to yt[n][co]
    u16* yt = (j ? y2t : y1t) + (size_t)b * N_ * 64;
    #pragma unroll
    for (int nt = 0; nt < 2; ++nt) {
        float sh = shiftA[j * 64 + co0 + nt * 16 + l16];
        #pragma unroll
        for (int r = 0; r < 4; ++r) {
            float yv = acc[nt][r] + sh;
            float sg = 1.f / (1.f + __expf(-yv));
            int n = h * 64 + w0 + kk * 4 + r;
            yt[(size_t)n * 64 + co0 + nt * 16 + l16] = h2u((_Float16)(yv * sg));
        }
    }
}

// ---------------------------------------------------------------------------
// K2: softmax stats via MFMA (unchanged; inputs now conv-produced yt).
// ---------------------------------------------------------------------------
__global__ __launch_bounds__(256) void stats_mfma_kernel(
    const u16* __restrict__ y1t, const u16* __restrict__ y2t,
    float* __restrict__ part)   // part[b][4][n][2]
{
    int blk = blockIdx.x;
    int mc = blk & 3;
    int nt = (blk >> 2) & 63;
    int b  = blk >> 8;
    int n0 = nt * 64;
    int t = threadIdx.x;
    int w = t >> 6, lane = t & 63;
    int l16 = lane & 15, kk = lane >> 4;
    const u16* yt1b = y1t + (size_t)b * N_ * CK_;
    const u16* yt2b = y2t + (size_t)b * N_ * CK_;

    int nw = n0 + w * 16;
    const u16* ap = yt2b + (size_t)(nw + l16) * CK_ + kk * 8;
    half8 a0 = *(const half8*)(const void*)ap;
    half8 a1 = *(const half8*)(const void*)(ap + 32);

    float rmax[4] = {-3.0e38f, -3.0e38f, -3.0e38f, -3.0e38f};
    float rsum[4] = {0.f, 0.f, 0.f, 0.f};
    int mbase = mc * 1024;

    for (int mi = 0; mi < 16; ++mi) {
        int m0 = mbase + mi * 64;
        #pragma unroll
        for (int ms = 0; ms < 4; ++ms) {
            const u16* bp = yt1b + (size_t)(m0 + ms * 16 + l16) * CK_ + kk * 8;
            half8 b0 = *(const half8*)(const void*)bp;
            half8 b1 = *(const half8*)(const void*)(bp + 32);
            f32x4 acc = {0.f, 0.f, 0.f, 0.f};
            acc = __builtin_amdgcn_mfma_f32_16x16x32_f16(a0, b0, acc, 0, 0, 0);
            acc = __builtin_amdgcn_mfma_f32_16x16x32_f16(a1, b1, acc, 0, 0, 0);
            #pragma unroll
            for (int r = 0; r < 4; ++r) {
                float c = acc[r];
                float M = fmaxf(rmax[r], c);
                rsum[r] = rsum[r] * __expf(rmax[r] - M) + __expf(c - M);
                rmax[r] = M;
            }
        }
    }
    #pragma unroll
    for (int r = 0; r < 4; ++r) {
        float M = rmax[r], S = rsum[r];
        #pragma unroll
        for (int d = 1; d < 16; d <<= 1) {
            float Mo = __shfl_xor(M, d, 64);
            float So = __shfl_xor(S, d, 64);
            float Mn = fmaxf(M, Mo);
            S = S * __expf(M - Mn) + So * __expf(Mo - Mn);
            M = Mn;
        }
        if (l16 == 0) {
            int n = nw + kk * 4 + r;
            size_t o = (((size_t)b * 4 + mc) * N_ + n) * 2;
            part[o]     = M;
            part[o + 1] = S;
        }
    }
}

__global__ __launch_bounds__(256) void stats_final_kernel(
    const float* __restrict__ part, float* __restrict__ rowmax, float* __restrict__ rowinv)
{
    int i = blockIdx.x * 256 + threadIdx.x;   // B*N = 8192
    if (i >= B_ * N_) return;
    int b = i / N_, n = i % N_;
    float M = -3.0e38f, S = 0.f;
    #pragma unroll
    for (int c = 0; c < 4; ++c) {
        size_t o = (((size_t)b * 4 + c) * N_ + n) * 2;
        float Mc = part[o], Sc = part[o + 1];
        float Mn = fmaxf(M, Mc);
        S = S * __expf(M - Mn) + Sc * __expf(Mc - Mn);
        M = Mn;
    }
    rowmax[i] = M;
    rowinv[i] = 1.f / S;
}

// ---------------------------------------------------------------------------
// K3: cw via MFMA, identical c chain to stats (unchanged).
// ---------------------------------------------------------------------------
__global__ __launch_bounds__(256) void cw_mfma_kernel(
    const u16* __restrict__ y1t, const u16* __restrict__ y2t,
    const float* __restrict__ rowmax, const float* __restrict__ rowinv,
    u16* __restrict__ cwt)
{
    __shared__ float Ms[64], Ivs[64];
    int blk = blockIdx.x;
    int mt = blk & 15;
    int nt = (blk >> 4) & 63;
    int b  = blk >> 10;
    int n0 = nt * 64, m0 = mt * 256;
    int t = threadIdx.x;
    int w = t >> 6, lane = t & 63;
    int l16 = lane & 15, kk = lane >> 4;
    if (t < 64) {
        Ms[t]  = rowmax[b * N_ + n0 + t];
        Ivs[t] = rowinv[b * N_ + n0 + t];
    }
    const u16* yt1b = y1t + (size_t)b * N_ * CK_;
    const u16* yt2b = y2t + (size_t)b * N_ * CK_;

    half8 A0[4], A1[4];
    #pragma unroll
    for (int ns = 0; ns < 4; ++ns) {
        const u16* ap = yt2b + (size_t)(n0 + ns * 16 + l16) * CK_ + kk * 8;
        A0[ns] = *(const half8*)(const void*)ap;
        A1[ns] = *(const half8*)(const void*)(ap + 32);
    }
    __syncthreads();

    int mw = m0 + w * 64;
    #pragma unroll
    for (int ms = 0; ms < 4; ++ms) {
        const u16* bp = yt1b + (size_t)(mw + ms * 16 + l16) * CK_ + kk * 8;
        half8 B0 = *(const half8*)(const void*)bp;
        half8 B1 = *(const half8*)(const void*)(bp + 32);
        int m = mw + ms * 16 + l16;
        u16* orow = cwt + ((size_t)(b * N_ + m)) * N_ + n0;
        #pragma unroll
        for (int ns = 0; ns < 4; ++ns) {
            f32x4 acc = {0.f, 0.f, 0.f, 0.f};
            acc = __builtin_amdgcn_mfma_f32_16x16x32_f16(A0[ns], B0, acc, 0, 0, 0);
            acc = __builtin_amdgcn_mfma_f32_16x16x32_f16(A1[ns], B1, acc, 0, 0, 0);
            int nl = ns * 16 + kk * 4;
            half4 p;
            #pragma unroll
            for (int r = 0; r < 4; ++r)
                p[r] = (_Float16)(__expf(acc[r] - Ms[nl + r]) * Ivs[nl + r]);
            *(half4*)(void*)(orow + nl) = p;
        }
    }
}

// ---------------------------------------------------------------------------
// K4: out[b][c][m] = sum_n x[c][n]*cw[n][m] via fp16 MFMA (unchanged).
// ---------------------------------------------------------------------------
__global__ __launch_bounds__(512, 4) void gemm_out_kernel(
    const u16* __restrict__ xh, const u16* __restrict__ cwt, float* __restrict__ out)
{
    int blk = blockIdx.x;
    int mt = blk & 127;
    int b  = blk >> 7;
    int m0 = mt * 32;
    int t = threadIdx.x;
    int lane = t & 63;
    int wv = t >> 6;
    int l16 = lane & 15;
    int kk  = lane >> 4;

    f32x4 acc[4][2] = {};
    const u16* apos = xh + (size_t)b * C_ * N_ + (size_t)(wv * 64 + l16) * N_ + kk * 8;
    const u16* bpos = cwt + (size_t)b * N_ * N_ + (size_t)(m0 + l16) * N_ + kk * 8;

    #pragma unroll 2
    for (int nt = 0; nt < 128; ++nt) {
        int n2 = nt * 32;
        half8 a[4], bb[2];
        #pragma unroll
        for (int ci = 0; ci < 4; ++ci)
            a[ci] = *(const half8*)(const void*)(apos + (size_t)ci * 16 * N_ + n2);
        #pragma unroll
        for (int mi = 0; mi < 2; ++mi)
            bb[mi] = *(const half8*)(const void*)(bpos + (size_t)mi * 16 * N_ + n2);
        #pragma unroll
        for (int ci = 0; ci < 4; ++ci)
            #pragma unroll
            for (int mi = 0; mi < 2; ++mi)
                acc[ci][mi] = __builtin_amdgcn_mfma_f32_16x16x32_f16(a[ci], bb[mi], acc[ci][mi], 0, 0, 0);
    }
    #pragma unroll
    for (int ci = 0; ci < 4; ++ci)
        #pragma unroll
        for (int mi = 0; mi < 2; ++mi)
            #pragma unroll
            for (int r = 0; r < 4; ++r)
                out[((size_t)(b * C_ + wv * 64 + ci * 16 + kk * 4 + r)) * N_ + m0 + mi * 16 + l16]
                    = acc[ci][mi][r];
}

// ---------------------------------------------------------------------------
extern "C" void kernel_launch(void* const* d_in, const int* in_sizes, int n_in,
                              void* d_out, int out_size, void* d_ws, size_t ws_size,
                              hipStream_t stream) {
    const float* x  = (const float*)d_in[0];
    const float* w1 = (const float*)d_in[1];
    const float* g1 = (const float*)d_in[2];
    const float* b1 = (const float*)d_in[3];
    const float* m1 = (const float*)d_in[4];
    const float* v1 = (const float*)d_in[5];
    const float* w2 = (const float*)d_in[6];
    const float* g2 = (const float*)d_in[7];
    const float* b2 = (const float*)d_in[8];
    const float* m2 = (const float*)d_in[9];
    const float* v2 = (const float*)d_in[10];
    float* out = (float*)d_out;

    constexpr size_t SHIFT_N = 2ULL * CK_;              // 128 f32
    constexpr size_t ROW_N   = (size_t)B_ * N_;         // 8192 f32
    constexpr size_t PART_N  = (size_t)B_ * 4 * N_ * 2; // 65536 f32
    constexpr size_t WH_N    = 2ULL * 9 * CK_ * C_;     // 589824 u16
    constexpr size_t XH_N    = (size_t)B_ * C_ * N_;    // 4194304 u16
    constexpr size_t CWT_N   = (size_t)B_ * N_ * N_;    // 33554432 u16
    constexpr size_t YT_N    = (size_t)B_ * N_ * CK_;   // 524288 u16

    float* ws = (float*)d_ws;
    float* shiftA = ws;
    float* rowmax = shiftA + SHIFT_N;
    float* rowinv = rowmax + ROW_N;
    float* part   = rowinv + ROW_N;
    float* f32_end = part + PART_N;
    u16*   wh     = (u16*)f32_end;
    u16*   xh     = wh + WH_N;
    u16*   xt     = xh + XH_N;
    u16*   cwt    = xt + XH_N;
    u16*   y1t    = cwt + CWT_N;
    u16*   y2t    = y1t + YT_N;
    (void)ws_size; (void)in_sizes; (void)n_in; (void)out_size;

    prep_weights_kernel<<<2304, 256, 0, stream>>>(w1, g1, b1, m1, v1,
                                                  w2, g2, b2, m2, v2, wh, shiftA);
    cast_x_kernel<<<2048, 256, 0, stream>>>(x, xh);
    transpose_x_kernel<<<256, 256, 0, stream>>>(x, xt);
    conv_mfma_kernel<<<256, 512, 0, stream>>>(xt, wh, shiftA, y1t, y2t);
    stats_mfma_kernel<<<512, 256, 0, stream>>>(y1t, y2t, part);
    stats_final_kernel<<<32, 256, 0, stream>>>(part, rowmax, rowinv);
    cw_mfma_kernel<<<2048, 256, 0, stream>>>(y1t, y2t, rowmax, rowinv, cwt);
    gemm_out_kernel<<<256, 512, 0, stream>>>(xh, cwt, out);
}

// Round 9
// 277.137 us; speedup vs baseline: 7.3183x; 1.3339x over previous
//
#include <hip/hip_runtime.h>

#define BN_EPS 1e-5f
#define B_ 2
#define C_ 512
#define CK_ 64
#define N_ 4096

typedef unsigned short u16;
typedef _Float16 half8 __attribute__((ext_vector_type(8)));
typedef _Float16 half4 __attribute__((ext_vector_type(4)));
typedef float f32x4 __attribute__((ext_vector_type(4)));

static __device__ inline u16 h2u(_Float16 h) {
    union { _Float16 h; u16 u; } x; x.h = h; return x.u;
}

// ---------------------------------------------------------------------------
// K0: fold BN scale into conv weights -> fp16 wh[j][tap][co][c]; shift[j][co] f32
// ---------------------------------------------------------------------------
__global__ __launch_bounds__(256) void prep_weights_kernel(
    const float* __restrict__ w1, const float* __restrict__ g1, const float* __restrict__ b1,
    const float* __restrict__ m1, const float* __restrict__ v1,
    const float* __restrict__ w2, const float* __restrict__ g2, const float* __restrict__ b2,
    const float* __restrict__ m2, const float* __restrict__ v2,
    u16* __restrict__ wh, float* __restrict__ shiftA)
{
    int idx = blockIdx.x * 256 + threadIdx.x;    // 2*9*64*512 = 589824 exactly
    int c   = idx & 511;
    int co  = (idx >> 9) & 63;
    int tap = (idx >> 15) % 9;
    int j   = idx / (9 << 15);
    const float* w = j ? w2 : w1;
    const float* g = j ? g2 : g1;
    const float* v = j ? v2 : v1;
    float scale = g[co] / sqrtf(v[co] + BN_EPS);
    float val = w[((size_t)co * C_ + c) * 9 + tap] * scale;
    wh[idx] = h2u((_Float16)val);
    if (idx < 2 * CK_) {
        int jj = idx >> 6, cc = idx & 63;
        const float* gg = jj ? g2 : g1;
        const float* vv = jj ? v2 : v1;
        const float* bb = jj ? b2 : b1;
        const float* mm = jj ? m2 : m1;
        float sc = gg[cc] / sqrtf(vv[cc] + BN_EPS);
        shiftA[idx] = bb[cc] - mm[cc] * sc;
    }
}

// ---------------------------------------------------------------------------
// K0b: cast x (fp32) -> fp16 xh, same [b][c][n] layout (attn_fused A operand)
// ---------------------------------------------------------------------------
__global__ __launch_bounds__(256) void cast_x_kernel(
    const float* __restrict__ x, u16* __restrict__ xh)
{
    int i = (blockIdx.x * 256 + threadIdx.x) * 8;
    float4 v0 = *(const float4*)(x + i);
    float4 v1 = *(const float4*)(x + i + 4);
    half8 h;
    h[0] = (_Float16)v0.x; h[1] = (_Float16)v0.y; h[2] = (_Float16)v0.z; h[3] = (_Float16)v0.w;
    h[4] = (_Float16)v1.x; h[5] = (_Float16)v1.y; h[6] = (_Float16)v1.z; h[7] = (_Float16)v1.w;
    *(half8*)(void*)(xh + i) = h;
}

// ---------------------------------------------------------------------------
// K0c: transpose x [b][c][n] f32 -> xt [b][n][512c] fp16 (conv staging source).
// ---------------------------------------------------------------------------
__global__ __launch_bounds__(256) void transpose_x_kernel(
    const float* __restrict__ x, u16* __restrict__ xt)
{
    int blk = blockIdx.x;
    int nb = blk & 15;
    int kg = (blk >> 4) & 7;
    int b  = blk >> 7;
    int n = nb * 256 + threadIdx.x;
    const float* sp = x + (size_t)b * C_ * N_ + n;
    u16* dp = xt + ((size_t)(b * N_ + n)) * C_;
    #pragma unroll
    for (int kc = 0; kc < 8; ++kc) {
        int c0 = kg * 64 + kc * 8;
        half8 h;
        #pragma unroll
        for (int q = 0; q < 8; ++q)
            h[q] = (_Float16)sp[(size_t)(c0 + q) * N_];
        *(half8*)(void*)(dp + c0) = h;
    }
}

// ---------------------------------------------------------------------------
// K1: conv3x3 + BN + SiLU via implicit-GEMM MFMA (unchanged from r8).
// ---------------------------------------------------------------------------
__global__ __launch_bounds__(512) void conv_mfma_kernel(
    const u16* __restrict__ xt, const u16* __restrict__ wh,
    const float* __restrict__ shiftA,
    u16* __restrict__ y1t, u16* __restrict__ y2t)
{
    __shared__ __align__(16) _Float16 xs[3 * 66 * 40];   // [r][wi][40]
    __shared__ __align__(16) _Float16 wsm[9 * 64 * 40];  // [tap][co][40]
    int blk = blockIdx.x;
    int h = blk & 63;
    int j = (blk >> 6) & 1;
    int b = blk >> 7;
    int t = threadIdx.x;
    int wave = t >> 6, lane = t & 63;
    int l16 = lane & 15, kk = lane >> 4;
    int w0  = (wave & 3) * 16;
    int co0 = (wave >> 2) * 32;

    const u16* xtb = xt + (size_t)b * N_ * C_;
    const u16* whj = wh + (size_t)j * 9 * 64 * C_;

    f32x4 acc[2] = {};

    for (int cc = 0; cc < 16; ++cc) {
        __syncthreads();
        for (int i = t; i < 792; i += 512) {
            int c8 = i & 3;
            int wi = (i >> 2) % 66;
            int r  = i / 264;
            int row = h - 1 + r;
            half8 v = {};
            if (row >= 0 && row < 64 && wi >= 1 && wi <= 64)
                v = *(const half8*)(const void*)(xtb
                      + ((size_t)(row * 64 + wi - 1)) * C_ + cc * 32 + c8 * 8);
            *(half8*)(void*)&xs[(r * 66 + wi) * 40 + c8 * 8] = v;
        }
        for (int i = t; i < 2304; i += 512) {
            int c8 = i & 3;
            int co = (i >> 2) & 63;
            int tap = i >> 8;
            *(half8*)(void*)&wsm[(tap * 64 + co) * 40 + c8 * 8] =
                *(const half8*)(const void*)(whj
                    + ((size_t)(tap * 64 + co)) * C_ + cc * 32 + c8 * 8);
        }
        __syncthreads();
        #pragma unroll
        for (int tap = 0; tap < 9; ++tap) {
            int dh = tap / 3, dw = tap - dh * 3;
            int wi = w0 + l16 + dw;
            half8 a  = *(const half8*)(const void*)&xs[(dh * 66 + wi) * 40 + kk * 8];
            half8 b0 = *(const half8*)(const void*)&wsm[(tap * 64 + co0 + l16) * 40 + kk * 8];
            half8 b1 = *(const half8*)(const void*)&wsm[(tap * 64 + co0 + 16 + l16) * 40 + kk * 8];
            acc[0] = __builtin_amdgcn_mfma_f32_16x16x32_f16(a, b0, acc[0], 0, 0, 0);
            acc[1] = __builtin_amdgcn_mfma_f32_16x16x32_f16(a, b1, acc[1], 0, 0, 0);
        }
    }
    u16* yt = (j ? y2t : y1t) + (size_t)b * N_ * 64;
    #pragma unroll
    for (int nt = 0; nt < 2; ++nt) {
        float sh = shiftA[j * 64 + co0 + nt * 16 + l16];
        #pragma unroll
        for (int r = 0; r < 4; ++r) {
            float yv = acc[nt][r] + sh;
            float sg = 1.f / (1.f + __expf(-yv));
            int n = h * 64 + w0 + kk * 4 + r;
            yt[(size_t)n * 64 + co0 + nt * 16 + l16] = h2u((_Float16)(yv * sg));
        }
    }
}

// ---------------------------------------------------------------------------
// K2: softmax stats via MFMA (unchanged).
// ---------------------------------------------------------------------------
__global__ __launch_bounds__(256) void stats_mfma_kernel(
    const u16* __restrict__ y1t, const u16* __restrict__ y2t,
    float* __restrict__ part)   // part[b][4][n][2]
{
    int blk = blockIdx.x;
    int mc = blk & 3;
    int nt = (blk >> 2) & 63;
    int b  = blk >> 8;
    int n0 = nt * 64;
    int t = threadIdx.x;
    int w = t >> 6, lane = t & 63;
    int l16 = lane & 15, kk = lane >> 4;
    const u16* yt1b = y1t + (size_t)b * N_ * CK_;
    const u16* yt2b = y2t + (size_t)b * N_ * CK_;

    int nw = n0 + w * 16;
    const u16* ap = yt2b + (size_t)(nw + l16) * CK_ + kk * 8;
    half8 a0 = *(const half8*)(const void*)ap;
    half8 a1 = *(const half8*)(const void*)(ap + 32);

    float rmax[4] = {-3.0e38f, -3.0e38f, -3.0e38f, -3.0e38f};
    float rsum[4] = {0.f, 0.f, 0.f, 0.f};
    int mbase = mc * 1024;

    for (int mi = 0; mi < 16; ++mi) {
        int m0 = mbase + mi * 64;
        #pragma unroll
        for (int ms = 0; ms < 4; ++ms) {
            const u16* bp = yt1b + (size_t)(m0 + ms * 16 + l16) * CK_ + kk * 8;
            half8 b0 = *(const half8*)(const void*)bp;
            half8 b1 = *(const half8*)(const void*)(bp + 32);
            f32x4 acc = {0.f, 0.f, 0.f, 0.f};
            acc = __builtin_amdgcn_mfma_f32_16x16x32_f16(a0, b0, acc, 0, 0, 0);
            acc = __builtin_amdgcn_mfma_f32_16x16x32_f16(a1, b1, acc, 0, 0, 0);
            #pragma unroll
            for (int r = 0; r < 4; ++r) {
                float c = acc[r];
                float M = fmaxf(rmax[r], c);
                rsum[r] = rsum[r] * __expf(rmax[r] - M) + __expf(c - M);
                rmax[r] = M;
            }
        }
    }
    #pragma unroll
    for (int r = 0; r < 4; ++r) {
        float M = rmax[r], S = rsum[r];
        #pragma unroll
        for (int d = 1; d < 16; d <<= 1) {
            float Mo = __shfl_xor(M, d, 64);
            float So = __shfl_xor(S, d, 64);
            float Mn = fmaxf(M, Mo);
            S = S * __expf(M - Mn) + So * __expf(Mo - Mn);
            M = Mn;
        }
        if (l16 == 0) {
            int n = nw + kk * 4 + r;
            size_t o = (((size_t)b * 4 + mc) * N_ + n) * 2;
            part[o]     = M;
            part[o + 1] = S;
        }
    }
}

__global__ __launch_bounds__(256) void stats_final_kernel(
    const float* __restrict__ part, float* __restrict__ rowmax, float* __restrict__ rowinv)
{
    int i = blockIdx.x * 256 + threadIdx.x;   // B*N = 8192
    if (i >= B_ * N_) return;
    int b = i / N_, n = i % N_;
    float M = -3.0e38f, S = 0.f;
    #pragma unroll
    for (int c = 0; c < 4; ++c) {
        size_t o = (((size_t)b * 4 + c) * N_ + n) * 2;
        float Mc = part[o], Sc = part[o + 1];
        float Mn = fmaxf(M, Mc);
        S = S * __expf(M - Mn) + Sc * __expf(Mc - Mn);
        M = Mn;
    }
    rowmax[i] = M;
    rowinv[i] = 1.f / S;
}

// ---------------------------------------------------------------------------
// K3 (NEW): fused cw + out.  Never materializes cw.
// Block = (b, cb(2 x 256c), mb(64 x 64m)); 512 thr / 8 waves; loop 64 n-chunks:
//   phase-1: P[64n][64m] = exp(c - M)*inv via MFMA, EXACT stats chain; -> LDS
//   phase-2: acc[256c][64m] += x[256c][64n] @ P  (x via global_load_lds,
//            XOR-pre-swizzled source cols; P rows padded to 72 halfs)
// ---------------------------------------------------------------------------
__global__ __launch_bounds__(512) void attn_fused_kernel(
    const u16* __restrict__ xh, const u16* __restrict__ y1t, const u16* __restrict__ y2t,
    const float* __restrict__ rowmax, const float* __restrict__ rowinv,
    float* __restrict__ out)
{
    __shared__ __align__(16) _Float16 xls[256 * 64];  // [c_loc][8 col8-groups] swz
    __shared__ __align__(16) _Float16 pls[64 * 72];   // [m_loc][72]
    int blk = blockIdx.x;
    int mb = blk & 63;
    int cb = (blk >> 6) & 1;
    int b  = blk >> 7;
    int c0 = cb * 256, m0 = mb * 64;
    int t = threadIdx.x;
    int w = t >> 6, lane = t & 63;
    int l16 = lane & 15, kk = lane >> 4;

    int p1n = w & 3;      // phase-1: n 16-group
    int p1q = w >> 2;     // phase-1: m half
    int wc  = w & 3;      // phase-2: c quarter (64 rows)
    int wm  = w >> 2;     // phase-2: m half (32)

    const u16* xb   = xh  + (size_t)b * C_ * N_;
    const u16* y1b  = y1t + (size_t)b * N_ * 64;
    const u16* y2b  = y2t + (size_t)b * N_ * 64;
    const float* Mrow = rowmax + b * N_;
    const float* Irow = rowinv + b * N_;

    // hoist y1 (B) fragments for this block's m-range: 4 x half8 = 16 VGPR
    half8 By[2][2];
    #pragma unroll
    for (int ms = 0; ms < 2; ++ms)
        #pragma unroll
        for (int g = 0; g < 2; ++g)
            By[ms][g] = *(const half8*)(const void*)(y1b
                + (size_t)(m0 + p1q * 32 + ms * 16 + l16) * 64 + g * 32 + kk * 8);

    f32x4 acc[4][2] = {};

    for (int nc = 0; nc < 64; ++nc) {
        __syncthreads();   // prior phase-2 done with xls/pls
        // stage x[256c][64n]: 2048 16B-slots, 4 rounds x 8 waves x 64 lanes.
        // slot s -> row r=s/8, col8=s&7 holds global n-group (col8 ^ (r&7)).
        #pragma unroll
        for (int rd = 0; rd < 4; ++rd) {
            int sbase = rd * 512 + w * 64;     // wave-uniform base slot
            int s = sbase + lane;
            int r = s >> 3, c8 = s & 7;
            const u16* gsrc = xb + (size_t)(c0 + r) * N_ + nc * 64 + ((c8 ^ (r & 7)) * 8);
            __builtin_amdgcn_global_load_lds(
                (const __attribute__((address_space(1))) void*)gsrc,
                (__attribute__((address_space(3))) void*)((char*)xls + sbase * 16),
                16, 0, 0);
        }
        // phase-1: P chunk, chain identical to stats_mfma
        {
            const u16* ap = y2b + (size_t)(nc * 64 + p1n * 16 + l16) * 64 + kk * 8;
            half8 a0 = *(const half8*)(const void*)ap;
            half8 a1 = *(const half8*)(const void*)(ap + 32);
            float Mr[4], Ir[4];
            #pragma unroll
            for (int r = 0; r < 4; ++r) {
                int n = nc * 64 + p1n * 16 + kk * 4 + r;
                Mr[r] = Mrow[n]; Ir[r] = Irow[n];
            }
            #pragma unroll
            for (int ms = 0; ms < 2; ++ms) {
                f32x4 pa = {0.f, 0.f, 0.f, 0.f};
                pa = __builtin_amdgcn_mfma_f32_16x16x32_f16(a0, By[ms][0], pa, 0, 0, 0);
                pa = __builtin_amdgcn_mfma_f32_16x16x32_f16(a1, By[ms][1], pa, 0, 0, 0);
                int mloc = p1q * 32 + ms * 16 + l16;
                half4 pv;
                #pragma unroll
                for (int r = 0; r < 4; ++r)
                    pv[r] = (_Float16)(__expf(pa[r] - Mr[r]) * Ir[r]);
                *(half4*)(void*)&pls[mloc * 72 + p1n * 16 + kk * 4] = pv;
            }
        }
        __syncthreads();   // x staged (vmcnt drained) + P written
        // phase-2: acc += x @ P
        #pragma unroll
        for (int g = 0; g < 2; ++g) {
            half8 Ax[4];
            #pragma unroll
            for (int ci = 0; ci < 4; ++ci) {
                int row = wc * 64 + ci * 16 + l16;
                int q8 = (g * 4 + kk) ^ (row & 7);
                Ax[ci] = *(const half8*)(const void*)&xls[row * 64 + q8 * 8];
            }
            half8 Bp[2];
            #pragma unroll
            for (int mi = 0; mi < 2; ++mi) {
                int mloc = wm * 32 + mi * 16 + l16;
                Bp[mi] = *(const half8*)(const void*)&pls[mloc * 72 + g * 32 + kk * 8];
            }
            #pragma unroll
            for (int ci = 0; ci < 4; ++ci)
                #pragma unroll
                for (int mi = 0; mi < 2; ++mi)
                    acc[ci][mi] = __builtin_amdgcn_mfma_f32_16x16x32_f16(
                        Ax[ci], Bp[mi], acc[ci][mi], 0, 0, 0);
        }
    }
    #pragma unroll
    for (int ci = 0; ci < 4; ++ci)
        #pragma unroll
        for (int mi = 0; mi < 2; ++mi)
            #pragma unroll
            for (int r = 0; r < 4; ++r)
                out[(size_t)(b * C_ + c0 + wc * 64 + ci * 16 + kk * 4 + r) * N_
                    + m0 + wm * 32 + mi * 16 + l16] = acc[ci][mi][r];
}

// ---------------------------------------------------------------------------
extern "C" void kernel_launch(void* const* d_in, const int* in_sizes, int n_in,
                              void* d_out, int out_size, void* d_ws, size_t ws_size,
                              hipStream_t stream) {
    const float* x  = (const float*)d_in[0];
    const float* w1 = (const float*)d_in[1];
    const float* g1 = (const float*)d_in[2];
    const float* b1 = (const float*)d_in[3];
    const float* m1 = (const float*)d_in[4];
    const float* v1 = (const float*)d_in[5];
    const float* w2 = (const float*)d_in[6];
    const float* g2 = (const float*)d_in[7];
    const float* b2 = (const float*)d_in[8];
    const float* m2 = (const float*)d_in[9];
    const float* v2 = (const float*)d_in[10];
    float* out = (float*)d_out;

    constexpr size_t SHIFT_N = 2ULL * CK_;              // 128 f32
    constexpr size_t ROW_N   = (size_t)B_ * N_;         // 8192 f32
    constexpr size_t PART_N  = (size_t)B_ * 4 * N_ * 2; // 65536 f32
    constexpr size_t WH_N    = 2ULL * 9 * CK_ * C_;     // 589824 u16
    constexpr size_t XH_N    = (size_t)B_ * C_ * N_;    // 4194304 u16
    constexpr size_t YT_N    = (size_t)B_ * N_ * CK_;   // 524288 u16

    float* ws = (float*)d_ws;
    float* shiftA = ws;
    float* rowmax = shiftA + SHIFT_N;
    float* rowinv = rowmax + ROW_N;
    float* part   = rowinv + ROW_N;
    float* f32_end = part + PART_N;
    u16*   wh     = (u16*)f32_end;
    u16*   xh     = wh + WH_N;
    u16*   xt     = xh + XH_N;
    u16*   y1t    = xt + XH_N;
    u16*   y2t    = y1t + YT_N;
    (void)ws_size; (void)in_sizes; (void)n_in; (void)out_size;

    prep_weights_kernel<<<2304, 256, 0, stream>>>(w1, g1, b1, m1, v1,
                                                  w2, g2, b2, m2, v2, wh, shiftA);
    cast_x_kernel<<<2048, 256, 0, stream>>>(x, xh);
    transpose_x_kernel<<<256, 256, 0, stream>>>(x, xt);
    conv_mfma_kernel<<<256, 512, 0, stream>>>(xt, wh, shiftA, y1t, y2t);
    stats_mfma_kernel<<<512, 256, 0, stream>>>(y1t, y2t, part);
    stats_final_kernel<<<32, 256, 0, stream>>>(part, rowmax, rowinv);
    attn_fused_kernel<<<256, 512, 0, stream>>>(xh, y1t, y2t, rowmax, rowinv, out);
}

// Round 10
// 274.910 us; speedup vs baseline: 7.3776x; 1.0081x over previous
//
#include <hip/hip_runtime.h>

#define BN_EPS 1e-5f
#define B_ 2
#define C_ 512
#define CK_ 64
#define N_ 4096

typedef unsigned short u16;
typedef _Float16 half8 __attribute__((ext_vector_type(8)));
typedef _Float16 half4 __attribute__((ext_vector_type(4)));
typedef float f32x4 __attribute__((ext_vector_type(4)));

static __device__ inline u16 h2u(_Float16 h) {
    union { _Float16 h; u16 u; } x; x.h = h; return x.u;
}

// ---------------------------------------------------------------------------
// K0: fold BN scale into conv weights -> fp16 wh[j][tap][co][c]; shift[j][co] f32
// ---------------------------------------------------------------------------
__global__ __launch_bounds__(256) void prep_weights_kernel(
    const float* __restrict__ w1, const float* __restrict__ g1, const float* __restrict__ b1,
    const float* __restrict__ m1, const float* __restrict__ v1,
    const float* __restrict__ w2, const float* __restrict__ g2, const float* __restrict__ b2,
    const float* __restrict__ m2, const float* __restrict__ v2,
    u16* __restrict__ wh, float* __restrict__ shiftA)
{
    int idx = blockIdx.x * 256 + threadIdx.x;    // 2*9*64*512 = 589824 exactly
    int c   = idx & 511;
    int co  = (idx >> 9) & 63;
    int tap = (idx >> 15) % 9;
    int j   = idx / (9 << 15);
    const float* w = j ? w2 : w1;
    const float* g = j ? g2 : g1;
    const float* v = j ? v2 : v1;
    float scale = g[co] / sqrtf(v[co] + BN_EPS);
    float val = w[((size_t)co * C_ + c) * 9 + tap] * scale;
    wh[idx] = h2u((_Float16)val);
    if (idx < 2 * CK_) {
        int jj = idx >> 6, cc = idx & 63;
        const float* gg = jj ? g2 : g1;
        const float* vv = jj ? v2 : v1;
        const float* bb = jj ? b2 : b1;
        const float* mm = jj ? m2 : m1;
        float sc = gg[cc] / sqrtf(vv[cc] + BN_EPS);
        shiftA[idx] = bb[cc] - mm[cc] * sc;
    }
}

// ---------------------------------------------------------------------------
// K0b: cast x (fp32) -> fp16 xh, same [b][c][n] layout
// ---------------------------------------------------------------------------
__global__ __launch_bounds__(256) void cast_x_kernel(
    const float* __restrict__ x, u16* __restrict__ xh)
{
    int i = (blockIdx.x * 256 + threadIdx.x) * 8;
    float4 v0 = *(const float4*)(x + i);
    float4 v1 = *(const float4*)(x + i + 4);
    half8 h;
    h[0] = (_Float16)v0.x; h[1] = (_Float16)v0.y; h[2] = (_Float16)v0.z; h[3] = (_Float16)v0.w;
    h[4] = (_Float16)v1.x; h[5] = (_Float16)v1.y; h[6] = (_Float16)v1.z; h[7] = (_Float16)v1.w;
    *(half8*)(void*)(xh + i) = h;
}

// ---------------------------------------------------------------------------
// K0c: transpose x [b][c][n] f32 -> xt [b][n][512c] fp16 (conv staging source).
// ---------------------------------------------------------------------------
__global__ __launch_bounds__(256) void transpose_x_kernel(
    const float* __restrict__ x, u16* __restrict__ xt)
{
    int blk = blockIdx.x;
    int nb = blk & 15;
    int kg = (blk >> 4) & 7;
    int b  = blk >> 7;
    int n = nb * 256 + threadIdx.x;
    const float* sp = x + (size_t)b * C_ * N_ + n;
    u16* dp = xt + ((size_t)(b * N_ + n)) * C_;
    #pragma unroll
    for (int kc = 0; kc < 8; ++kc) {
        int c0 = kg * 64 + kc * 8;
        half8 h;
        #pragma unroll
        for (int q = 0; q < 8; ++q)
            h[q] = (_Float16)sp[(size_t)(c0 + q) * N_];
        *(half8*)(void*)(dp + c0) = h;
    }
}

// ---------------------------------------------------------------------------
// K1: conv3x3 + BN + SiLU via implicit-GEMM MFMA (unchanged).
// ---------------------------------------------------------------------------
__global__ __launch_bounds__(512) void conv_mfma_kernel(
    const u16* __restrict__ xt, const u16* __restrict__ wh,
    const float* __restrict__ shiftA,
    u16* __restrict__ y1t, u16* __restrict__ y2t)
{
    __shared__ __align__(16) _Float16 xs[3 * 66 * 40];   // [r][wi][40]
    __shared__ __align__(16) _Float16 wsm[9 * 64 * 40];  // [tap][co][40]
    int blk = blockIdx.x;
    int h = blk & 63;
    int j = (blk >> 6) & 1;
    int b = blk >> 7;
    int t = threadIdx.x;
    int wave = t >> 6, lane = t & 63;
    int l16 = lane & 15, kk = lane >> 4;
    int w0  = (wave & 3) * 16;
    int co0 = (wave >> 2) * 32;

    const u16* xtb = xt + (size_t)b * N_ * C_;
    const u16* whj = wh + (size_t)j * 9 * 64 * C_;

    f32x4 acc[2] = {};

    for (int cc = 0; cc < 16; ++cc) {
        __syncthreads();
        for (int i = t; i < 792; i += 512) {
            int c8 = i & 3;
            int wi = (i >> 2) % 66;
            int r  = i / 264;
            int row = h - 1 + r;
            half8 v = {};
            if (row >= 0 && row < 64 && wi >= 1 && wi <= 64)
                v = *(const half8*)(const void*)(xtb
                      + ((size_t)(row * 64 + wi - 1)) * C_ + cc * 32 + c8 * 8);
            *(half8*)(void*)&xs[(r * 66 + wi) * 40 + c8 * 8] = v;
        }
        for (int i = t; i < 2304; i += 512) {
            int c8 = i & 3;
            int co = (i >> 2) & 63;
            int tap = i >> 8;
            *(half8*)(void*)&wsm[(tap * 64 + co) * 40 + c8 * 8] =
                *(const half8*)(const void*)(whj
                    + ((size_t)(tap * 64 + co)) * C_ + cc * 32 + c8 * 8);
        }
        __syncthreads();
        #pragma unroll
        for (int tap = 0; tap < 9; ++tap) {
            int dh = tap / 3, dw = tap - dh * 3;
            int wi = w0 + l16 + dw;
            half8 a  = *(const half8*)(const void*)&xs[(dh * 66 + wi) * 40 + kk * 8];
            half8 b0 = *(const half8*)(const void*)&wsm[(tap * 64 + co0 + l16) * 40 + kk * 8];
            half8 b1 = *(const half8*)(const void*)&wsm[(tap * 64 + co0 + 16 + l16) * 40 + kk * 8];
            acc[0] = __builtin_amdgcn_mfma_f32_16x16x32_f16(a, b0, acc[0], 0, 0, 0);
            acc[1] = __builtin_amdgcn_mfma_f32_16x16x32_f16(a, b1, acc[1], 0, 0, 0);
        }
    }
    u16* yt = (j ? y2t : y1t) + (size_t)b * N_ * 64;
    #pragma unroll
    for (int nt = 0; nt < 2; ++nt) {
        float sh = shiftA[j * 64 + co0 + nt * 16 + l16];
        #pragma unroll
        for (int r = 0; r < 4; ++r) {
            float yv = acc[nt][r] + sh;
            float sg = 1.f / (1.f + __expf(-yv));
            int n = h * 64 + w0 + kk * 4 + r;
            yt[(size_t)n * 64 + co0 + nt * 16 + l16] = h2u((_Float16)(yv * sg));
        }
    }
}

// ---------------------------------------------------------------------------
// K2: softmax stats via MFMA (unchanged).
// ---------------------------------------------------------------------------
__global__ __launch_bounds__(256) void stats_mfma_kernel(
    const u16* __restrict__ y1t, const u16* __restrict__ y2t,
    float* __restrict__ part)   // part[b][4][n][2]
{
    int blk = blockIdx.x;
    int mc = blk & 3;
    int nt = (blk >> 2) & 63;
    int b  = blk >> 8;
    int n0 = nt * 64;
    int t = threadIdx.x;
    int w = t >> 6, lane = t & 63;
    int l16 = lane & 15, kk = lane >> 4;
    const u16* yt1b = y1t + (size_t)b * N_ * CK_;
    const u16* yt2b = y2t + (size_t)b * N_ * CK_;

    int nw = n0 + w * 16;
    const u16* ap = yt2b + (size_t)(nw + l16) * CK_ + kk * 8;
    half8 a0 = *(const half8*)(const void*)ap;
    half8 a1 = *(const half8*)(const void*)(ap + 32);

    float rmax[4] = {-3.0e38f, -3.0e38f, -3.0e38f, -3.0e38f};
    float rsum[4] = {0.f, 0.f, 0.f, 0.f};
    int mbase = mc * 1024;

    for (int mi = 0; mi < 16; ++mi) {
        int m0 = mbase + mi * 64;
        #pragma unroll
        for (int ms = 0; ms < 4; ++ms) {
            const u16* bp = yt1b + (size_t)(m0 + ms * 16 + l16) * CK_ + kk * 8;
            half8 b0 = *(const half8*)(const void*)bp;
            half8 b1 = *(const half8*)(const void*)(bp + 32);
            f32x4 acc = {0.f, 0.f, 0.f, 0.f};
            acc = __builtin_amdgcn_mfma_f32_16x16x32_f16(a0, b0, acc, 0, 0, 0);
            acc = __builtin_amdgcn_mfma_f32_16x16x32_f16(a1, b1, acc, 0, 0, 0);
            #pragma unroll
            for (int r = 0; r < 4; ++r) {
                float c = acc[r];
                float M = fmaxf(rmax[r], c);
                rsum[r] = rsum[r] * __expf(rmax[r] - M) + __expf(c - M);
                rmax[r] = M;
            }
        }
    }
    #pragma unroll
    for (int r = 0; r < 4; ++r) {
        float M = rmax[r], S = rsum[r];
        #pragma unroll
        for (int d = 1; d < 16; d <<= 1) {
            float Mo = __shfl_xor(M, d, 64);
            float So = __shfl_xor(S, d, 64);
            float Mn = fmaxf(M, Mo);
            S = S * __expf(M - Mn) + So * __expf(Mo - Mn);
            M = Mn;
        }
        if (l16 == 0) {
            int n = nw + kk * 4 + r;
            size_t o = (((size_t)b * 4 + mc) * N_ + n) * 2;
            part[o]     = M;
            part[o + 1] = S;
        }
    }
}

__global__ __launch_bounds__(256) void stats_final_kernel(
    const float* __restrict__ part, float* __restrict__ rowmax, float* __restrict__ rowinv)
{
    int i = blockIdx.x * 256 + threadIdx.x;   // B*N = 8192
    if (i >= B_ * N_) return;
    int b = i / N_, n = i % N_;
    float M = -3.0e38f, S = 0.f;
    #pragma unroll
    for (int c = 0; c < 4; ++c) {
        size_t o = (((size_t)b * 4 + c) * N_ + n) * 2;
        float Mc = part[o], Sc = part[o + 1];
        float Mn = fmaxf(M, Mc);
        S = S * __expf(M - Mn) + Sc * __expf(Mc - Mn);
        M = Mn;
    }
    rowmax[i] = M;
    rowinv[i] = 1.f / S;
}

// ---------------------------------------------------------------------------
// K3: fused cw + out.  r10: c-tile 128, 4 waves/block, grid 512 -> 4+ blocks/CU
// (r9 was 1 block/CU; barrier drains exposed full staging latency).
// Block = (b, cb(4 x 128c), mb(64 x 64m)); loop 64 n-chunks:
//   phase-1: P[64n][64m] = exp(c - M)*inv via MFMA (stats-identical chain) -> LDS
//   phase-2: acc[128c][64m] += x[128c][64n] @ P  (x via global_load_lds,
//            XOR-pre-swizzled source cols; P rows padded to 72 halfs)
// XCD-swizzle: 512 blocks = 8 XCD x 64 -> each XCD owns all mb of one (b?,cb).
// ---------------------------------------------------------------------------
__global__ __launch_bounds__(256, 4) void attn_fused_kernel(
    const u16* __restrict__ xh, const u16* __restrict__ y1t, const u16* __restrict__ y2t,
    const float* __restrict__ rowmax, const float* __restrict__ rowinv,
    float* __restrict__ out)
{
    __shared__ __align__(16) _Float16 xls[128 * 64];  // [c_loc][8 col8-groups] swz
    __shared__ __align__(16) _Float16 pls[64 * 72];   // [m_loc][72]
    int gid = blockIdx.x;                 // 512 blocks
    int blk = (gid & 7) * 64 + (gid >> 3);  // bijective XCD swizzle (512 % 8 == 0)
    int mb = blk & 63;
    int cb = (blk >> 6) & 3;
    int b  = blk >> 8;
    int c0 = cb * 128, m0 = mb * 64;
    int t = threadIdx.x;
    int w = t >> 6, lane = t & 63;        // 4 waves
    int l16 = lane & 15, kk = lane >> 4;

    const u16* xb   = xh  + (size_t)b * C_ * N_;
    const u16* y1b  = y1t + (size_t)b * N_ * 64;
    const u16* y2b  = y2t + (size_t)b * N_ * 64;
    const float* Mrow = rowmax + b * N_;
    const float* Irow = rowinv + b * N_;

    // hoist y1 (B) fragments for the full 64-m range: 8 x half8 = 32 VGPR
    half8 By[4][2];
    #pragma unroll
    for (int ms = 0; ms < 4; ++ms)
        #pragma unroll
        for (int g = 0; g < 2; ++g)
            By[ms][g] = *(const half8*)(const void*)(y1b
                + (size_t)(m0 + ms * 16 + l16) * 64 + g * 32 + kk * 8);

    f32x4 acc[2][4] = {};

    for (int nc = 0; nc < 64; ++nc) {
        __syncthreads();   // prior phase-2 done with xls/pls
        // stage x[128c][64n]: 1024 16B-slots, 4 rounds x 4 waves x 64 lanes.
        // slot s -> row r=s/8, col8=s&7 holds global n-group (col8 ^ (r&7)).
        #pragma unroll
        for (int rd = 0; rd < 4; ++rd) {
            int sbase = rd * 256 + w * 64;     // wave-uniform base slot
            int s = sbase + lane;
            int r = s >> 3, c8 = s & 7;
            const u16* gsrc = xb + (size_t)(c0 + r) * N_ + nc * 64 + ((c8 ^ (r & 7)) * 8);
            __builtin_amdgcn_global_load_lds(
                (const __attribute__((address_space(1))) void*)gsrc,
                (__attribute__((address_space(3))) void*)((char*)xls + sbase * 16),
                16, 0, 0);
        }
        // phase-1: P chunk; wave w owns n-16-group w, all 64 m
        {
            const u16* ap = y2b + (size_t)(nc * 64 + w * 16 + l16) * 64 + kk * 8;
            half8 a0 = *(const half8*)(const void*)ap;
            half8 a1 = *(const half8*)(const void*)(ap + 32);
            float Mr[4], Ir[4];
            #pragma unroll
            for (int r = 0; r < 4; ++r) {
                int n = nc * 64 + w * 16 + kk * 4 + r;
                Mr[r] = Mrow[n]; Ir[r] = Irow[n];
            }
            #pragma unroll
            for (int ms = 0; ms < 4; ++ms) {
                f32x4 pa = {0.f, 0.f, 0.f, 0.f};
                pa = __builtin_amdgcn_mfma_f32_16x16x32_f16(a0, By[ms][0], pa, 0, 0, 0);
                pa = __builtin_amdgcn_mfma_f32_16x16x32_f16(a1, By[ms][1], pa, 0, 0, 0);
                int mloc = ms * 16 + l16;
                half4 pv;
                #pragma unroll
                for (int r = 0; r < 4; ++r)
                    pv[r] = (_Float16)(__expf(pa[r] - Mr[r]) * Ir[r]);
                *(half4*)(void*)&pls[mloc * 72 + w * 16 + kk * 4] = pv;
            }
        }
        __syncthreads();   // x staged (vmcnt drained) + P written
        // phase-2: acc += x @ P ; wave w owns c rows w*32..w*32+31, all 64 m
        #pragma unroll
        for (int g = 0; g < 2; ++g) {
            half8 Ax[2];
            #pragma unroll
            for (int ci = 0; ci < 2; ++ci) {
                int row = w * 32 + ci * 16 + l16;
                int q8 = (g * 4 + kk) ^ (row & 7);
                Ax[ci] = *(const half8*)(const void*)&xls[row * 64 + q8 * 8];
            }
            half8 Bp[4];
            #pragma unroll
            for (int mi = 0; mi < 4; ++mi) {
                int mloc = mi * 16 + l16;
                Bp[mi] = *(const half8*)(const void*)&pls[mloc * 72 + g * 32 + kk * 8];
            }
            #pragma unroll
            for (int ci = 0; ci < 2; ++ci)
                #pragma unroll
                for (int mi = 0; mi < 4; ++mi)
                    acc[ci][mi] = __builtin_amdgcn_mfma_f32_16x16x32_f16(
                        Ax[ci], Bp[mi], acc[ci][mi], 0, 0, 0);
        }
    }
    #pragma unroll
    for (int ci = 0; ci < 2; ++ci)
        #pragma unroll
        for (int mi = 0; mi < 4; ++mi)
            #pragma unroll
            for (int r = 0; r < 4; ++r)
                out[(size_t)(b * C_ + c0 + w * 32 + ci * 16 + kk * 4 + r) * N_
                    + m0 + mi * 16 + l16] = acc[ci][mi][r];
}

// ---------------------------------------------------------------------------
extern "C" void kernel_launch(void* const* d_in, const int* in_sizes, int n_in,
                              void* d_out, int out_size, void* d_ws, size_t ws_size,
                              hipStream_t stream) {
    const float* x  = (const float*)d_in[0];
    const float* w1 = (const float*)d_in[1];
    const float* g1 = (const float*)d_in[2];
    const float* b1 = (const float*)d_in[3];
    const float* m1 = (const float*)d_in[4];
    const float* v1 = (const float*)d_in[5];
    const float* w2 = (const float*)d_in[6];
    const float* g2 = (const float*)d_in[7];
    const float* b2 = (const float*)d_in[8];
    const float* m2 = (const float*)d_in[9];
    const float* v2 = (const float*)d_in[10];
    float* out = (float*)d_out;

    constexpr size_t SHIFT_N = 2ULL * CK_;              // 128 f32
    constexpr size_t ROW_N   = (size_t)B_ * N_;         // 8192 f32
    constexpr size_t PART_N  = (size_t)B_ * 4 * N_ * 2; // 65536 f32
    constexpr size_t WH_N    = 2ULL * 9 * CK_ * C_;     // 589824 u16
    constexpr size_t XH_N    = (size_t)B_ * C_ * N_;    // 4194304 u16
    constexpr size_t YT_N    = (size_t)B_ * N_ * CK_;   // 524288 u16

    float* ws = (float*)d_ws;
    float* shiftA = ws;
    float* rowmax = shiftA + SHIFT_N;
    float* rowinv = rowmax + ROW_N;
    float* part   = rowinv + ROW_N;
    float* f32_end = part + PART_N;
    u16*   wh     = (u16*)f32_end;
    u16*   xh     = wh + WH_N;
    u16*   xt     = xh + XH_N;
    u16*   y1t    = xt + XH_N;
    u16*   y2t    = y1t + YT_N;
    (void)ws_size; (void)in_sizes; (void)n_in; (void)out_size;

    prep_weights_kernel<<<2304, 256, 0, stream>>>(w1, g1, b1, m1, v1,
                                                  w2, g2, b2, m2, v2, wh, shiftA);
    cast_x_kernel<<<2048, 256, 0, stream>>>(x, xh);
    transpose_x_kernel<<<256, 256, 0, stream>>>(x, xt);
    conv_mfma_kernel<<<256, 512, 0, stream>>>(xt, wh, shiftA, y1t, y2t);
    stats_mfma_kernel<<<512, 256, 0, stream>>>(y1t, y2t, part);
    stats_final_kernel<<<32, 256, 0, stream>>>(part, rowmax, rowinv);
    attn_fused_kernel<<<512, 256, 0, stream>>>(xh, y1t, y2t, rowmax, rowinv, out);
}

// Round 13
// 249.190 us; speedup vs baseline: 8.1390x; 1.1032x over previous
//
#include <hip/hip_runtime.h>

#define BN_EPS 1e-5f
#define B_ 2
#define C_ 512
#define CK_ 64
#define N_ 4096

typedef unsigned short u16;
typedef _Float16 half8 __attribute__((ext_vector_type(8)));
typedef _Float16 half4 __attribute__((ext_vector_type(4)));
typedef float f32x4 __attribute__((ext_vector_type(4)));

static __device__ inline u16 h2u(_Float16 h) {
    union { _Float16 h; u16 u; } x; x.h = h; return x.u;
}

// ---------------------------------------------------------------------------
// K0: fold BN scale into conv weights -> fp16 wh[j][tap][co][c]; shift[j][co] f32
// ---------------------------------------------------------------------------
__global__ __launch_bounds__(256) void prep_weights_kernel(
    const float* __restrict__ w1, const float* __restrict__ g1, const float* __restrict__ b1,
    const float* __restrict__ m1, const float* __restrict__ v1,
    const float* __restrict__ w2, const float* __restrict__ g2, const float* __restrict__ b2,
    const float* __restrict__ m2, const float* __restrict__ v2,
    u16* __restrict__ wh, float* __restrict__ shiftA)
{
    int idx = blockIdx.x * 256 + threadIdx.x;    // 2*9*64*512 = 589824 exactly
    int c   = idx & 511;
    int co  = (idx >> 9) & 63;
    int tap = (idx >> 15) % 9;
    int j   = idx / (9 << 15);
    const float* w = j ? w2 : w1;
    const float* g = j ? g2 : g1;
    const float* v = j ? v2 : v1;
    float scale = g[co] / sqrtf(v[co] + BN_EPS);
    float val = w[((size_t)co * C_ + c) * 9 + tap] * scale;
    wh[idx] = h2u((_Float16)val);
    if (idx < 2 * CK_) {
        int jj = idx >> 6, cc = idx & 63;
        const float* gg = jj ? g2 : g1;
        const float* vv = jj ? v2 : v1;
        const float* bb = jj ? b2 : b1;
        const float* mm = jj ? m2 : m1;
        float sc = gg[cc] / sqrtf(vv[cc] + BN_EPS);
        shiftA[idx] = bb[cc] - mm[cc] * sc;
    }
}

// ---------------------------------------------------------------------------
// K0b: cast x (fp32) -> fp16 xh, same [b][c][n] layout
// ---------------------------------------------------------------------------
__global__ __launch_bounds__(256) void cast_x_kernel(
    const float* __restrict__ x, u16* __restrict__ xh)
{
    int i = (blockIdx.x * 256 + threadIdx.x) * 8;
    float4 v0 = *(const float4*)(x + i);
    float4 v1 = *(const float4*)(x + i + 4);
    half8 h;
    h[0] = (_Float16)v0.x; h[1] = (_Float16)v0.y; h[2] = (_Float16)v0.z; h[3] = (_Float16)v0.w;
    h[4] = (_Float16)v1.x; h[5] = (_Float16)v1.y; h[6] = (_Float16)v1.z; h[7] = (_Float16)v1.w;
    *(half8*)(void*)(xh + i) = h;
}

// ---------------------------------------------------------------------------
// K0c: transpose x [b][c][n] f32 -> xt [b][n][512c] fp16 (conv staging source).
// ---------------------------------------------------------------------------
__global__ __launch_bounds__(256) void transpose_x_kernel(
    const float* __restrict__ x, u16* __restrict__ xt)
{
    int blk = blockIdx.x;
    int nb = blk & 15;
    int kg = (blk >> 4) & 7;
    int b  = blk >> 7;
    int n = nb * 256 + threadIdx.x;
    const float* sp = x + (size_t)b * C_ * N_ + n;
    u16* dp = xt + ((size_t)(b * N_ + n)) * C_;
    #pragma unroll
    for (int kc = 0; kc < 8; ++kc) {
        int c0 = kg * 64 + kc * 8;
        half8 h;
        #pragma unroll
        for (int q = 0; q < 8; ++q)
            h[q] = (_Float16)sp[(size_t)(c0 + q) * N_];
        *(half8*)(void*)(dp + c0) = h;
    }
}

// ---------------------------------------------------------------------------
// K1: conv3x3 + BN + SiLU via implicit-GEMM MFMA (unchanged).
// ---------------------------------------------------------------------------
__global__ __launch_bounds__(512) void conv_mfma_kernel(
    const u16* __restrict__ xt, const u16* __restrict__ wh,
    const float* __restrict__ shiftA,
    u16* __restrict__ y1t, u16* __restrict__ y2t)
{
    __shared__ __align__(16) _Float16 xs[3 * 66 * 40];   // [r][wi][40]
    __shared__ __align__(16) _Float16 wsm[9 * 64 * 40];  // [tap][co][40]
    int blk = blockIdx.x;
    int h = blk & 63;
    int j = (blk >> 6) & 1;
    int b = blk >> 7;
    int t = threadIdx.x;
    int wave = t >> 6, lane = t & 63;
    int l16 = lane & 15, kk = lane >> 4;
    int w0  = (wave & 3) * 16;
    int co0 = (wave >> 2) * 32;

    const u16* xtb = xt + (size_t)b * N_ * C_;
    const u16* whj = wh + (size_t)j * 9 * 64 * C_;

    f32x4 acc[2] = {};

    for (int cc = 0; cc < 16; ++cc) {
        __syncthreads();
        for (int i = t; i < 792; i += 512) {
            int c8 = i & 3;
            int wi = (i >> 2) % 66;
            int r  = i / 264;
            int row = h - 1 + r;
            half8 v = {};
            if (row >= 0 && row < 64 && wi >= 1 && wi <= 64)
                v = *(const half8*)(const void*)(xtb
                      + ((size_t)(row * 64 + wi - 1)) * C_ + cc * 32 + c8 * 8);
            *(half8*)(void*)&xs[(r * 66 + wi) * 40 + c8 * 8] = v;
        }
        for (int i = t; i < 2304; i += 512) {
            int c8 = i & 3;
            int co = (i >> 2) & 63;
            int tap = i >> 8;
            *(half8*)(void*)&wsm[(tap * 64 + co) * 40 + c8 * 8] =
                *(const half8*)(const void*)(whj
                    + ((size_t)(tap * 64 + co)) * C_ + cc * 32 + c8 * 8);
        }
        __syncthreads();
        #pragma unroll
        for (int tap = 0; tap < 9; ++tap) {
            int dh = tap / 3, dw = tap - dh * 3;
            int wi = w0 + l16 + dw;
            half8 a  = *(const half8*)(const void*)&xs[(dh * 66 + wi) * 40 + kk * 8];
            half8 b0 = *(const half8*)(const void*)&wsm[(tap * 64 + co0 + l16) * 40 + kk * 8];
            half8 b1 = *(const half8*)(const void*)&wsm[(tap * 64 + co0 + 16 + l16) * 40 + kk * 8];
            acc[0] = __builtin_amdgcn_mfma_f32_16x16x32_f16(a, b0, acc[0], 0, 0, 0);
            acc[1] = __builtin_amdgcn_mfma_f32_16x16x32_f16(a, b1, acc[1], 0, 0, 0);
        }
    }
    u16* yt = (j ? y2t : y1t) + (size_t)b * N_ * 64;
    #pragma unroll
    for (int nt = 0; nt < 2; ++nt) {
        float sh = shiftA[j * 64 + co0 + nt * 16 + l16];
        #pragma unroll
        for (int r = 0; r < 4; ++r) {
            float yv = acc[nt][r] + sh;
            float sg = 1.f / (1.f + __expf(-yv));
            int n = h * 64 + w0 + kk * 4 + r;
            yt[(size_t)n * 64 + co0 + nt * 16 + l16] = h2u((_Float16)(yv * sg));
        }
    }
}

// ---------------------------------------------------------------------------
// K2: softmax stats via MFMA (unchanged).
// ---------------------------------------------------------------------------
__global__ __launch_bounds__(256) void stats_mfma_kernel(
    const u16* __restrict__ y1t, const u16* __restrict__ y2t,
    float* __restrict__ part)   // part[b][4][n][2]
{
    int blk = blockIdx.x;
    int mc = blk & 3;
    int nt = (blk >> 2) & 63;
    int b  = blk >> 8;
    int n0 = nt * 64;
    int t = threadIdx.x;
    int w = t >> 6, lane = t & 63;
    int l16 = lane & 15, kk = lane >> 4;
    const u16* yt1b = y1t + (size_t)b * N_ * CK_;
    const u16* yt2b = y2t + (size_t)b * N_ * CK_;

    int nw = n0 + w * 16;
    const u16* ap = yt2b + (size_t)(nw + l16) * CK_ + kk * 8;
    half8 a0 = *(const half8*)(const void*)ap;
    half8 a1 = *(const half8*)(const void*)(ap + 32);

    float rmax[4] = {-3.0e38f, -3.0e38f, -3.0e38f, -3.0e38f};
    float rsum[4] = {0.f, 0.f, 0.f, 0.f};
    int mbase = mc * 1024;

    for (int mi = 0; mi < 16; ++mi) {
        int m0 = mbase + mi * 64;
        #pragma unroll
        for (int ms = 0; ms < 4; ++ms) {
            const u16* bp = yt1b + (size_t)(m0 + ms * 16 + l16) * CK_ + kk * 8;
            half8 b0 = *(const half8*)(const void*)bp;
            half8 b1 = *(const half8*)(const void*)(bp + 32);
            f32x4 acc = {0.f, 0.f, 0.f, 0.f};
            acc = __builtin_amdgcn_mfma_f32_16x16x32_f16(a0, b0, acc, 0, 0, 0);
            acc = __builtin_amdgcn_mfma_f32_16x16x32_f16(a1, b1, acc, 0, 0, 0);
            #pragma unroll
            for (int r = 0; r < 4; ++r) {
                float c = acc[r];
                float M = fmaxf(rmax[r], c);
                rsum[r] = rsum[r] * __expf(rmax[r] - M) + __expf(c - M);
                rmax[r] = M;
            }
        }
    }
    #pragma unroll
    for (int r = 0; r < 4; ++r) {
        float M = rmax[r], S = rsum[r];
        #pragma unroll
        for (int d = 1; d < 16; d <<= 1) {
            float Mo = __shfl_xor(M, d, 64);
            float So = __shfl_xor(S, d, 64);
            float Mn = fmaxf(M, Mo);
            S = S * __expf(M - Mn) + So * __expf(Mo - Mn);
            M = Mn;
        }
        if (l16 == 0) {
            int n = nw + kk * 4 + r;
            size_t o = (((size_t)b * 4 + mc) * N_ + n) * 2;
            part[o]     = M;
            part[o + 1] = S;
        }
    }
}

__global__ __launch_bounds__(256) void stats_final_kernel(
    const float* __restrict__ part, float* __restrict__ rowmax, float* __restrict__ rowinv)
{
    int i = blockIdx.x * 256 + threadIdx.x;   // B*N = 8192
    if (i >= B_ * N_) return;
    int b = i / N_, n = i % N_;
    float M = -3.0e38f, S = 0.f;
    #pragma unroll
    for (int c = 0; c < 4; ++c) {
        size_t o = (((size_t)b * 4 + c) * N_ + n) * 2;
        float Mc = part[o], Sc = part[o + 1];
        float Mn = fmaxf(M, Mc);
        S = S * __expf(M - Mn) + Sc * __expf(Mc - Mn);
        M = Mn;
    }
    rowmax[i] = M;
    rowinv[i] = 1.f / S;
}

// ---------------------------------------------------------------------------
// K3: fused cw + out, r11: SINGLE-barrier double-buffered pipeline.
// r10 failure: 2 barriers/chunk, each draining vmcnt(0) right after the stage
// was issued -> zero load/compute overlap (MfmaUtil 17%).  Now: per chunk,
// {stage x[nc+1] -> xls[^1]; compute P[nc+1] -> pls[^1]; phase-2 on [cur];
// one __syncthreads()}.  The vmcnt drain at the barrier lands after a full
// compute phase.  y2 fragments register-prefetched 2 chunks ahead (T14).
// ---------------------------------------------------------------------------
__global__ __launch_bounds__(256, 2) void attn_fused_kernel(
    const u16* __restrict__ xh, const u16* __restrict__ y1t, const u16* __restrict__ y2t,
    const float* __restrict__ rowmax, const float* __restrict__ rowinv,
    float* __restrict__ out)
{
    __shared__ __align__(16) _Float16 xls[2][128 * 64];  // [c_loc][8 col8-grp] swz
    __shared__ __align__(16) _Float16 pls[2][64 * 72];   // [m_loc][72]
    int gid = blockIdx.x;                 // 512 blocks
    int blk = (gid & 7) * 64 + (gid >> 3);  // bijective XCD swizzle (512 % 8 == 0)
    int mb = blk & 63;
    int cb = (blk >> 6) & 3;
    int b  = blk >> 8;
    int c0 = cb * 128, m0 = mb * 64;
    int t = threadIdx.x;
    int w = t >> 6, lane = t & 63;        // 4 waves
    int l16 = lane & 15, kk = lane >> 4;

    const u16* xb   = xh  + (size_t)b * C_ * N_;
    const u16* y1b  = y1t + (size_t)b * N_ * 64;
    const u16* y2b  = y2t + (size_t)b * N_ * 64;
    const float* Mrow = rowmax + b * N_;
    const float* Irow = rowinv + b * N_;

    // hoist y1 (B) fragments for the full 64-m range: 8 x half8 = 32 VGPR
    half8 By[4][2];
    #pragma unroll
    for (int ms = 0; ms < 4; ++ms)
        #pragma unroll
        for (int g = 0; g < 2; ++g)
            By[ms][g] = *(const half8*)(const void*)(y1b
                + (size_t)(m0 + ms * 16 + l16) * 64 + g * 32 + kk * 8);

    auto load_a = [&](int nc, half8& a0, half8& a1) {
        const u16* ap = y2b + (size_t)(nc * 64 + w * 16 + l16) * 64 + kk * 8;
        a0 = *(const half8*)(const void*)ap;
        a1 = *(const half8*)(const void*)(ap + 32);
    };
    auto stage_x = [&](int buf, int nc) {
        #pragma unroll
        for (int rd = 0; rd < 4; ++rd) {
            int sbase = rd * 256 + w * 64;     // wave-uniform base slot
            int s = sbase + lane;
            int r = s >> 3, c8 = s & 7;
            const u16* gsrc = xb + (size_t)(c0 + r) * N_ + nc * 64 + ((c8 ^ (r & 7)) * 8);
            __builtin_amdgcn_global_load_lds(
                (const __attribute__((address_space(1))) void*)gsrc,
                (__attribute__((address_space(3))) void*)((char*)&xls[buf][0] + sbase * 16),
                16, 0, 0);
        }
    };
    auto compute_p = [&](int buf, int nc, half8 a0, half8 a1) {
        float Mr[4], Ir[4];
        #pragma unroll
        for (int r = 0; r < 4; ++r) {
            int n = nc * 64 + w * 16 + kk * 4 + r;
            Mr[r] = Mrow[n]; Ir[r] = Irow[n];
        }
        #pragma unroll
        for (int ms = 0; ms < 4; ++ms) {
            f32x4 pa = {0.f, 0.f, 0.f, 0.f};
            pa = __builtin_amdgcn_mfma_f32_16x16x32_f16(a0, By[ms][0], pa, 0, 0, 0);
            pa = __builtin_amdgcn_mfma_f32_16x16x32_f16(a1, By[ms][1], pa, 0, 0, 0);
            int mloc = ms * 16 + l16;
            half4 pv;
            #pragma unroll
            for (int r = 0; r < 4; ++r)
                pv[r] = (_Float16)(__expf(pa[r] - Mr[r]) * Ir[r]);
            *(half4*)(void*)&pls[buf][mloc * 72 + w * 16 + kk * 4] = pv;
        }
    };

    f32x4 acc[2][4] = {};
    auto phase2 = [&](int buf) {
        #pragma unroll
        for (int g = 0; g < 2; ++g) {
            half8 Ax[2];
            #pragma unroll
            for (int ci = 0; ci < 2; ++ci) {
                int row = w * 32 + ci * 16 + l16;
                int q8 = (g * 4 + kk) ^ (row & 7);
                Ax[ci] = *(const half8*)(const void*)&xls[buf][row * 64 + q8 * 8];
            }
            half8 Bp[4];
            #pragma unroll
            for (int mi = 0; mi < 4; ++mi) {
                int mloc = mi * 16 + l16;
                Bp[mi] = *(const half8*)(const void*)&pls[buf][mloc * 72 + g * 32 + kk * 8];
            }
            #pragma unroll
            for (int ci = 0; ci < 2; ++ci)
                #pragma unroll
                for (int mi = 0; mi < 4; ++mi)
                    acc[ci][mi] = __builtin_amdgcn_mfma_f32_16x16x32_f16(
                        Ax[ci], Bp[mi], acc[ci][mi], 0, 0, 0);
        }
    };

    // prologue: chunk 0 staged + P0 computed, a(chunk1) prefetched
    half8 a0c, a1c, a0n, a1n;
    load_a(0, a0c, a1c);
    stage_x(0, 0);
    compute_p(0, 0, a0c, a1c);
    load_a(1, a0n, a1n);
    __syncthreads();

    for (int nc = 0; nc < 63; ++nc) {
        int cur = nc & 1;
        stage_x(cur ^ 1, nc + 1);             // issue-early (lands by barrier)
        compute_p(cur ^ 1, nc + 1, a0n, a1n); // P for next chunk into other buf
        int pf = (nc + 2 > 63) ? 63 : nc + 2; // register-prefetch y2 2 ahead
        half8 t0, t1;
        load_a(pf, t0, t1);
        phase2(cur);                          // MFMA on current buffers
        __syncthreads();                      // single barrier per chunk
        a0n = t0; a1n = t1;
    }
    phase2(1);   // chunk 63 lives in buf 1 (written at nc=62)

    #pragma unroll
    for (int ci = 0; ci < 2; ++ci)
        #pragma unroll
        for (int mi = 0; mi < 4; ++mi)
            #pragma unroll
            for (int r = 0; r < 4; ++r)
                out[(size_t)(b * C_ + c0 + w * 32 + ci * 16 + kk * 4 + r) * N_
                    + m0 + mi * 16 + l16] = acc[ci][mi][r];
}

// ---------------------------------------------------------------------------
extern "C" void kernel_launch(void* const* d_in, const int* in_sizes, int n_in,
                              void* d_out, int out_size, void* d_ws, size_t ws_size,
                              hipStream_t stream) {
    const float* x  = (const float*)d_in[0];
    const float* w1 = (const float*)d_in[1];
    const float* g1 = (const float*)d_in[2];
    const float* b1 = (const float*)d_in[3];
    const float* m1 = (const float*)d_in[4];
    const float* v1 = (const float*)d_in[5];
    const float* w2 = (const float*)d_in[6];
    const float* g2 = (const float*)d_in[7];
    const float* b2 = (const float*)d_in[8];
    const float* m2 = (const float*)d_in[9];
    const float* v2 = (const float*)d_in[10];
    float* out = (float*)d_out;

    constexpr size_t SHIFT_N = 2ULL * CK_;              // 128 f32
    constexpr size_t ROW_N   = (size_t)B_ * N_;         // 8192 f32
    constexpr size_t PART_N  = (size_t)B_ * 4 * N_ * 2; // 65536 f32
    constexpr size_t WH_N    = 2ULL * 9 * CK_ * C_;     // 589824 u16
    constexpr size_t XH_N    = (size_t)B_ * C_ * N_;    // 4194304 u16
    constexpr size_t YT_N    = (size_t)B_ * N_ * CK_;   // 524288 u16

    float* ws = (float*)d_ws;
    float* shiftA = ws;
    float* rowmax = shiftA + SHIFT_N;
    float* rowinv = rowmax + ROW_N;
    float* part   = rowinv + ROW_N;
    float* f32_end = part + PART_N;
    u16*   wh     = (u16*)f32_end;
    u16*   xh     = wh + WH_N;
    u16*   xt     = xh + XH_N;
    u16*   y1t    = xt + XH_N;
    u16*   y2t    = y1t + YT_N;
    (void)ws_size; (void)in_sizes; (void)n_in; (void)out_size;

    prep_weights_kernel<<<2304, 256, 0, stream>>>(w1, g1, b1, m1, v1,
                                                  w2, g2, b2, m2, v2, wh, shiftA);
    cast_x_kernel<<<2048, 256, 0, stream>>>(x, xh);
    transpose_x_kernel<<<256, 256, 0, stream>>>(x, xt);
    conv_mfma_kernel<<<256, 512, 0, stream>>>(xt, wh, shiftA, y1t, y2t);
    stats_mfma_kernel<<<512, 256, 0, stream>>>(y1t, y2t, part);
    stats_final_kernel<<<32, 256, 0, stream>>>(part, rowmax, rowinv);
    attn_fused_kernel<<<512, 256, 0, stream>>>(xh, y1t, y2t, rowmax, rowinv, out);
}